// Round 11
// baseline (698.244 us; speedup 1.0000x reference)
//
#include <hip/hip_runtime.h>
#include <hip/hip_bf16.h>
#include <math.h>

// Problem constants (fixed by setup_inputs)
#define BB 4
#define NN 16384
#define SS 4096
#define D1 128
#define D2 256
#define C1 256   // mlp[0]
#define C2 128   // mlp[1]
#define MTOT (BB*NN)   // 65536

// knn decomposition. R17: QPT=4 — four independent select-chains per thread
// raise VALU work per candidate (152 cyc) above the invariant ~100cyc/cand
// per-wave stall that R8-R16 could not remove by occupancy/scheduling alone
// (153us constant across 4 configs; VGPR 20->32 with no time change).
#define QPT 4              // queries per thread
#define SCH 256            // candidates per chunk (4KB LDS)
#define NCH (SS/SCH)       // 16 chunks
#define PTH 128            // threads per partial block
#define LB  4              // load batch width (4 x float4 = 16 VGPR)

typedef _Float16 f16x8 __attribute__((ext_vector_type(8)));
typedef float f32x4  __attribute__((ext_vector_type(4)));
typedef int   i32x4  __attribute__((ext_vector_type(4)));

#define LPAD 40            // LDS row stride in fp16 elems (80B, 16B-aligned)

// ---------------------------------------------------------------------------
// Pack xyz2 into float4 {-2x, -2y, -2z, ||p||^2} (bit-exact vs reference:
// x(-2) is exact pow2 scaling, so (qq + cr2) + pw == (qq - 2*cr) + pw).
// ---------------------------------------------------------------------------
__global__ __launch_bounds__(256) void pack_kernel(
    const float* __restrict__ xyz2, float4* __restrict__ packed)
{
#pragma clang fp contract(off)
    int s = blockIdx.x * 256 + threadIdx.x;
    float px = xyz2[s*3+0], py = xyz2[s*3+1], pz = xyz2[s*3+2];
    float pp = (px*px + py*py) + pz*pz;
    packed[s] = make_float4(-2.0f*px, -2.0f*py, -2.0f*pz, pp);
}

// ---------------------------------------------------------------------------
// Convert W1, W2 to fp16 (RNE) once.
// ---------------------------------------------------------------------------
__global__ __launch_bounds__(256) void wcvt_kernel(
    const float* __restrict__ W1, const float* __restrict__ W2,
    _Float16* __restrict__ W1c, _Float16* __restrict__ W2c)
{
    int i = blockIdx.x * 256 + threadIdx.x;
    if (i < C1 * (D1 + D2)) W1c[i] = (_Float16)W1[i];
    if (i < C2 * C1)        W2c[i] = (_Float16)W2[i];
}

// ---------------------------------------------------------------------------
// 3-NN pass 1: exact fp32 distances (contract off), min/med3 distance chain +
// cndmask index chain, strict '<' with ascending candidate order (stable,
// == lax.top_k). HARD CONSTRAINT (R7): selection is discontinuous in the
// gathered features -> never approximate the distance or the comparison.
// R17: QPT=4, LB=4 register load batches + sched_barrier(0).
// ---------------------------------------------------------------------------
__global__ __launch_bounds__(PTH, 8) void knn3_partial_kernel(
    const float* __restrict__ xyz1, const float4* __restrict__ packed,
    float* __restrict__ pd0, float* __restrict__ pd1, float* __restrict__ pd2,
    int* __restrict__ pi0, int* __restrict__ pi1, int* __restrict__ pi2)
{
#pragma clang fp contract(off)
    __shared__ float4 pk[SCH];                       // 4 KB

    const int qblocks = NN / (PTH * QPT);            // 32
    const int b  = blockIdx.x / (qblocks * NCH);
    const int r  = blockIdx.x % (qblocks * NCH);
    const int qc = r / NCH;
    const int sc = r % NCH;

    const float4* src = packed + (size_t)b * SS + sc * SCH;
    for (int i = threadIdx.x; i < SCH; i += PTH) pk[i] = src[i];
    __syncthreads();

    float qx[QPT], qy[QPT], qz[QPT], qq[QPT];
    float e0[QPT], e1[QPT], e2[QPT];
    int   j0[QPT], j1[QPT], j2[QPT];
#pragma unroll
    for (int q = 0; q < QPT; ++q) {
        int n = qc * (PTH * QPT) + q * PTH + threadIdx.x;
        size_t m = (size_t)b * NN + n;
        qx[q] = xyz1[m*3+0]; qy[q] = xyz1[m*3+1]; qz[q] = xyz1[m*3+2];
        qq[q] = (qx[q]*qx[q] + qy[q]*qy[q]) + qz[q]*qz[q];
        e0[q] = 3.4e38f; e1[q] = 3.4e38f; e2[q] = 3.4e38f;
        j0[q] = 0; j1[q] = 0; j2[q] = 0;
    }

    auto proc = [&](float4 p, int s) {
#pragma clang fp contract(off)
#pragma unroll
        for (int q = 0; q < QPT; ++q) {
            float cr2 = (qx[q]*p.x + qy[q]*p.y) + qz[q]*p.z;   // == -2*cr exactly
            float d = (qq[q] + cr2) + p.w;
            d = fmaxf(d, 0.0f);
            bool c0 = d < e0[q], c1 = d < e1[q], c2 = d < e2[q];
            j2[q] = c1 ? j1[q] : (c2 ? s : j2[q]);
            j1[q] = c0 ? j0[q] : (c1 ? s : j1[q]);
            j0[q] = c0 ? s : j0[q];
            e2[q] = __builtin_amdgcn_fmed3f(e1[q], d, e2[q]);
            e1[q] = __builtin_amdgcn_fmed3f(e0[q], d, e1[q]);
            e0[q] = fminf(e0[q], d);
        }
    };

    for (int s = 0; s < SCH; s += LB) {
        float4 P[LB];
#pragma unroll
        for (int i = 0; i < LB; ++i) P[i] = pk[s + i];   // 4 x ds_read_b128
        __builtin_amdgcn_sched_barrier(0);               // pin loads before bodies
#pragma unroll
        for (int i = 0; i < LB; ++i) proc(P[i], s + i);
    }

#pragma unroll
    for (int q = 0; q < QPT; ++q) {
        int n = qc * (PTH * QPT) + q * PTH + threadIdx.x;
        size_t m = (size_t)b * NN + n;
        size_t o = (size_t)sc * MTOT + m;
        pd0[o] = e0[q]; pd1[o] = e1[q]; pd2[o] = e2[q];
        pi0[o] = sc*SCH + j0[q];
        pi1[o] = sc*SCH + j1[q];
        pi2[o] = sc*SCH + j2[q];
    }
}

// ---------------------------------------------------------------------------
// 3-NN pass 2: merge chunk triples (ascending chunk order, ascending j within
// chunk, strict '<') — identical scan order to a full ascending pass.
// SoA planes -> all loads lane-coalesced and mutually independent.
// ---------------------------------------------------------------------------
__global__ __launch_bounds__(256) void knn3_merge_kernel(
    const float* __restrict__ pd0, const float* __restrict__ pd1, const float* __restrict__ pd2,
    const int* __restrict__ pi0, const int* __restrict__ pi1, const int* __restrict__ pi2,
    int* __restrict__ idx_out, float* __restrict__ w_out)
{
#pragma clang fp contract(off)
    int m = blockIdx.x * 256 + threadIdx.x;
    int b = m / NN;

    float d0 = pd0[m], d1 = pd1[m], d2 = pd2[m];
    int   i0 = pi0[m], i1 = pi1[m], i2 = pi2[m];

#pragma unroll
    for (int c = 1; c < NCH; ++c) {
        size_t oc = (size_t)c * MTOT + m;
        float da = pd0[oc], db = pd1[oc], dc = pd2[oc];
        int   sa = pi0[oc], sb = pi1[oc], scv = pi2[oc];
        {
            float d = da; int s = sa;
            bool c0 = d < d0, c1 = d < d1, c2 = d < d2;
            d2 = c1 ? d1 : (c2 ? d : d2);  i2 = c1 ? i1 : (c2 ? s : i2);
            d1 = c0 ? d0 : (c1 ? d : d1);  i1 = c0 ? i0 : (c1 ? s : i1);
            d0 = c0 ? d : d0;              i0 = c0 ? s : i0;
        }
        {
            float d = db; int s = sb;
            bool c0 = d < d0, c1 = d < d1, c2 = d < d2;
            d2 = c1 ? d1 : (c2 ? d : d2);  i2 = c1 ? i1 : (c2 ? s : i2);
            d1 = c0 ? d0 : (c1 ? d : d1);  i1 = c0 ? i0 : (c1 ? s : i1);
            d0 = c0 ? d : d0;              i0 = c0 ? s : i0;
        }
        {
            float d = dc; int s = scv;
            bool c0 = d < d0, c1 = d < d1, c2 = d < d2;
            d2 = c1 ? d1 : (c2 ? d : d2);  i2 = c1 ? i1 : (c2 ? s : i2);
            d1 = c0 ? d0 : (c1 ? d : d1);  i1 = c0 ? i0 : (c1 ? s : i1);
            d0 = c0 ? d : d0;              i0 = c0 ? s : i0;
        }
    }
    float r0 = 1.0f / (d0 + 1e-8f);
    float r1 = 1.0f / (d1 + 1e-8f);
    float r2 = 1.0f / (d2 + 1e-8f);
    float inv = 1.0f / ((r0 + r1) + r2);
    idx_out[m*3+0] = b * SS + i0;
    idx_out[m*3+1] = b * SS + i1;
    idx_out[m*3+2] = b * SS + i2;
    w_out[m*3+0] = r0 * inv;
    w_out[m*3+1] = r1 * inv;
    w_out[m*3+2] = r2 * inv;
}

// ---------------------------------------------------------------------------
// fp16 MFMA GEMM, LDS double-buffered with ONE barrier per k-iter.
// C[M x N] = op(A[M x K]) @ W[N x K]^T (+ bias).
// Tile 64(M) x 128(N), 4 waves of 32x64, k-chunk 32 (16x16x32 f16 MFMA).
// ---------------------------------------------------------------------------
template<int K, typename AT, typename OT, bool BN_A, bool FUSE_STATS>
__global__ __launch_bounds__(256, 4) void gemm_mfma_kernel(
    const AT* __restrict__ A, int lda,
    const _Float16* __restrict__ W, int ldw,
    OT* __restrict__ C, int ldc,
    const float* __restrict__ bias,
    const float* __restrict__ scaleA, const float* __restrict__ shiftA,
    float* __restrict__ sumO, float* __restrict__ sqO)
{
    __shared__ _Float16 Ash[2][64 * LPAD];     // 2 x 5 KB
    __shared__ _Float16 Bsh[2][128 * LPAD];    // 2 x 10 KB

    const int tid = threadIdx.x;
    const int m0 = blockIdx.x * 64;
    const int n0 = blockIdx.y * 128;
    const int wave = tid >> 6, lane = tid & 63;
    const int ln = lane & 15, q4 = lane >> 4;
    const int wm = wave & 1, wn = wave >> 1;

    const int ar = tid >> 2, ak = (tid & 3) * 8;   // A staging: 64 rows x 32k
    const int br = tid >> 1, bk = (tid & 1) * 16;  // B staging: 128 rows x 32k

    f32x4 acc[2][4] = {};

    float  avF[8];      // used when AT == float
    f16x8  avH;         // used when AT == _Float16
    f16x8  bvA[2];

    {   // prologue prefetch k0 = 0
        if constexpr (__is_same(AT, float)) {
            const float* ap = A + (size_t)(m0 + ar) * lda + ak;
            *(float4*)&avF[0] = *(const float4*)ap;
            *(float4*)&avF[4] = *(const float4*)(ap + 4);
        } else {
            avH = *(const f16x8*)(A + (size_t)(m0 + ar) * lda + ak);
        }
        const _Float16* bp = W + (size_t)(n0 + br) * ldw + bk;
        bvA[0] = *(const f16x8*)bp;
        bvA[1] = *(const f16x8*)(bp + 8);
    }

    for (int k0 = 0; k0 < K; k0 += 32) {
        const int buf = (k0 >> 5) & 1;

        // ---- transform + store staged regs to LDS[buf] ----
        {
            float av[8];
            if constexpr (__is_same(AT, float)) {
#pragma unroll
                for (int i = 0; i < 8; ++i) av[i] = avF[i];
            } else {
#pragma unroll
                for (int i = 0; i < 8; ++i) av[i] = (float)avH[i];
            }
            if (BN_A) {
#pragma unroll
                for (int i = 0; i < 8; ++i) {
                    float sc = scaleA[k0 + ak + i];
                    float sh = shiftA[k0 + ak + i];
                    av[i] = fmaxf(av[i] * sc + sh, 0.0f);
                }
            }
            f16x8 vh;
#pragma unroll
            for (int i = 0; i < 8; ++i) vh[i] = (_Float16)av[i];
            *(f16x8*)&Ash[buf][ar * LPAD + ak] = vh;
            *(f16x8*)&Bsh[buf][br * LPAD + bk]     = bvA[0];
            *(f16x8*)&Bsh[buf][br * LPAD + bk + 8] = bvA[1];
        }
        __syncthreads();    // single barrier: writers of buf done; dbuf makes it safe

        // ---- issue next chunk's global loads (overlap with MFMA below) ----
        if (k0 + 32 < K) {
            if constexpr (__is_same(AT, float)) {
                const float* ap = A + (size_t)(m0 + ar) * lda + (k0 + 32) + ak;
                *(float4*)&avF[0] = *(const float4*)ap;
                *(float4*)&avF[4] = *(const float4*)(ap + 4);
            } else {
                avH = *(const f16x8*)(A + (size_t)(m0 + ar) * lda + (k0 + 32) + ak);
            }
            const _Float16* bp = W + (size_t)(n0 + br) * ldw + (k0 + 32) + bk;
            bvA[0] = *(const f16x8*)bp;
            bvA[1] = *(const f16x8*)(bp + 8);
        }

        // ---- fragments + MFMA ----
        f16x8 af[2];
#pragma unroll
        for (int mi = 0; mi < 2; ++mi) {
            int arow = wm * 32 + mi * 16 + ln;
            af[mi] = *(const f16x8*)&Ash[buf][arow * LPAD + q4 * 8];
        }
        f16x8 bf[4];
#pragma unroll
        for (int ni = 0; ni < 4; ++ni) {
            int brow = wn * 64 + ni * 16 + ln;
            bf[ni] = *(const f16x8*)&Bsh[buf][brow * LPAD + q4 * 8];
        }
#pragma unroll
        for (int mi = 0; mi < 2; ++mi)
#pragma unroll
            for (int ni = 0; ni < 4; ++ni)
                acc[mi][ni] = __builtin_amdgcn_mfma_f32_16x16x32_f16(af[mi], bf[ni], acc[mi][ni], 0, 0, 0);
    }

    // ---- epilogue ----  C/D layout: col = ln, row = q4*4 + r  (m89/m91)
#pragma unroll
    for (int ni = 0; ni < 4; ++ni) {
        int col = n0 + wn * 64 + ni * 16 + ln;
        float vb = bias ? bias[col] : 0.0f;
        float s = 0.0f, s2 = 0.0f;
#pragma unroll
        for (int mi = 0; mi < 2; ++mi) {
#pragma unroll
            for (int r = 0; r < 4; ++r) {
                int row_g = m0 + wm * 32 + mi * 16 + q4 * 4 + r;
                float v = acc[mi][ni][r] + vb;
                C[(size_t)row_g * ldc + col] = (OT)v;
                s += v; s2 += v * v;
            }
        }
        if (FUSE_STATS) {
            s  += __shfl_xor(s, 16);  s  += __shfl_xor(s, 32);
            s2 += __shfl_xor(s2, 16); s2 += __shfl_xor(s2, 32);
            if (q4 == 0) {
                atomicAdd(&sumO[col], s);
                atomicAdd(&sqO[col], s2);
            }
        }
    }
}

// ---------------------------------------------------------------------------
// Dedicated interp + bias + BN1-stats kernel.
// y1[m, :] = temp[m, :] + wa*P2[ia, :] + wb*P2[ib, :] + wc*P2[ic, :] + b1
// ---------------------------------------------------------------------------
__global__ __launch_bounds__(256, 8) void interp_stats_kernel(
    const float* __restrict__ temp,     // [MTOT x C1] fp32 gemm result
    const _Float16* __restrict__ P2,    // [BB*SS x C1] f16
    const int* __restrict__ idx3, const float* __restrict__ w3,
    const float* __restrict__ bias,
    _Float16* __restrict__ Y,           // [MTOT x C1] f16
    float* __restrict__ sumO, float* __restrict__ sqO)
{
    __shared__ float sred[2 * C1];      // 512 floats: [sum | sumsq]
    const int tid = threadIdx.x;
    const int sl  = tid & 31;           // col slice (8 cols)
    const int rg  = tid >> 5;           // 0..7
    const int m0  = blockIdx.x * 32;

    sred[tid] = 0.0f; sred[tid + 256] = 0.0f;
    __syncthreads();

    float bv[8];
    *(float4*)&bv[0] = *(const float4*)(bias + sl * 8);
    *(float4*)&bv[4] = *(const float4*)(bias + sl * 8 + 4);

    float sAcc[8]  = {0.f,0.f,0.f,0.f,0.f,0.f,0.f,0.f};
    float s2Acc[8] = {0.f,0.f,0.f,0.f,0.f,0.f,0.f,0.f};

#pragma unroll
    for (int rr = 0; rr < 4; ++rr) {
        const int row = m0 + rg * 4 + rr;
        const int*   ip = idx3 + (size_t)row * 3;
        const float* wp = w3   + (size_t)row * 3;
        int   ia = ip[0], ib = ip[1], ic = ip[2];
        float wa = wp[0], wb = wp[1], wc = wp[2];

        float av[8];
        const float* tp = temp + (size_t)row * C1 + sl * 8;
        *(float4*)&av[0] = *(const float4*)tp;
        *(float4*)&av[4] = *(const float4*)(tp + 4);
        f16x8 pa = *(const f16x8*)(P2 + (size_t)ia * C1 + sl * 8);
        f16x8 pb = *(const f16x8*)(P2 + (size_t)ib * C1 + sl * 8);
        f16x8 pc = *(const f16x8*)(P2 + (size_t)ic * C1 + sl * 8);

        f16x8 outv;
#pragma unroll
        for (int i = 0; i < 8; ++i) {
            float v = av[i];
            v += wa * (float)pa[i];
            v += wb * (float)pb[i];
            v += wc * (float)pc[i];
            v += bv[i];
            outv[i] = (_Float16)v;
            sAcc[i]  += v;
            s2Acc[i] += v * v;
        }
        *(f16x8*)(Y + (size_t)row * C1 + sl * 8) = outv;
    }

#pragma unroll
    for (int i = 0; i < 8; ++i) {
        atomicAdd(&sred[sl * 8 + i],       sAcc[i]);
        atomicAdd(&sred[256 + sl * 8 + i], s2Acc[i]);
    }
    __syncthreads();
    atomicAdd(&sumO[tid], sred[tid]);
    atomicAdd(&sqO[tid],  sred[tid + 256]);
}

// ---------------------------------------------------------------------------
__global__ void finalize_kernel(
    const float* __restrict__ sum, const float* __restrict__ sumsq,
    const float* __restrict__ g, const float* __restrict__ beta,
    int M, int C, float* __restrict__ scale, float* __restrict__ shift)
{
    int c = threadIdx.x;
    if (c >= C) return;
    float invM = 1.0f / (float)M;
    float mean = sum[c] * invM;
    float var = fmaxf(sumsq[c] * invM - mean * mean, 0.0f);
    float rstd = 1.0f / sqrtf(var + 1e-5f);
    float sc = g[c] * rstd;
    scale[c] = sc;
    shift[c] = beta[c] - mean * sc;
}

__global__ __launch_bounds__(256) void bnrelu_kernel(
    float* __restrict__ X, int total4, int C,
    const float* __restrict__ scale, const float* __restrict__ shift)
{
    int i = blockIdx.x * 256 + threadIdx.x;
    if (i >= total4) return;
    float4 v = ((const float4*)X)[i];
    int c = (i * 4) & (C - 1);      // C pow2, 4 | C -> no wrap within the 4
    v.x = fmaxf(v.x * scale[c+0] + shift[c+0], 0.0f);
    v.y = fmaxf(v.y * scale[c+1] + shift[c+1], 0.0f);
    v.z = fmaxf(v.z * scale[c+2] + shift[c+2], 0.0f);
    v.w = fmaxf(v.w * scale[c+3] + shift[c+3], 0.0f);
    ((float4*)X)[i] = v;
}

// ---------------------------------------------------------------------------
extern "C" void kernel_launch(void* const* d_in, const int* in_sizes, int n_in,
                              void* d_out, int out_size, void* d_ws, size_t ws_size,
                              hipStream_t stream) {
    const float* xyz1    = (const float*)d_in[0];
    const float* xyz2    = (const float*)d_in[1];
    const float* points1 = (const float*)d_in[2];
    const float* points2 = (const float*)d_in[3];
    const float* W1      = (const float*)d_in[4];
    const float* b1      = (const float*)d_in[5];
    const float* g1      = (const float*)d_in[6];
    const float* beta1   = (const float*)d_in[7];
    const float* W2      = (const float*)d_in[8];
    const float* b2      = (const float*)d_in[9];
    const float* g2      = (const float*)d_in[10];
    const float* beta2   = (const float*)d_in[11];
    float* out = (float*)d_out;

    // ws layout (byte offsets, 16B-aligned)
    char* ws = (char*)d_ws;
    size_t off = 0;
    int*   idx = (int*)(ws + off);            off += (size_t)MTOT*3*4;
    float* w   = (float*)(ws + off);          off += (size_t)MTOT*3*4;
    _Float16* P2h = (_Float16*)(ws + off);    off += (size_t)BB*SS*C1*2;    // 8 MB
    _Float16* y1h = (_Float16*)(ws + off);    off += (size_t)MTOT*C1*2;     // 32 MB
    float* stats = (float*)(ws + off);        off += 2048*4;
    float* sum1 = stats;            // 256
    float* sq1  = stats + 256;      // 256
    float* sum2 = stats + 512;      // 128
    float* sq2  = stats + 640;      // 128
    float* scale1 = stats + 768;    // 256
    float* shift1 = stats + 1024;   // 256
    float* scale2 = stats + 1280;   // 128
    float* shift2 = stats + 1408;   // 128
    float4* packed = (float4*)(ws + off);     off += (size_t)BB*SS*16;      // 1 MB
    _Float16* W1c = (_Float16*)(ws + off);    off += (size_t)C1*(D1+D2)*2;
    _Float16* W2c = (_Float16*)(ws + off);    off += (size_t)C2*C1*2;
    off = (off + 255) & ~(size_t)255;
    float* tempf = (float*)(ws + off);        off += (size_t)MTOT*C1*4;     // 64 MB
    // knn partials: 6 SoA planes of NCH*MTOT (25.2 MB total) alias the y1h
    // region (32 MB; y1h is written later, by interp_stats_kernel)
    float* pd0 = (float*)y1h;                 // NCH*MTOT floats (4.2 MB each)
    float* pd1 = pd0 + (size_t)NCH*MTOT;
    float* pd2 = pd1 + (size_t)NCH*MTOT;
    int*   pi0 = (int*)(pd2 + (size_t)NCH*MTOT);
    int*   pi1 = pi0 + (size_t)NCH*MTOT;
    int*   pi2 = pi1 + (size_t)NCH*MTOT;

    hipMemsetAsync(stats, 0, 768 * sizeof(float), stream);

    pack_kernel<<<(BB*SS)/256, 256, 0, stream>>>(xyz2, packed);
    wcvt_kernel<<<(C1*(D1+D2))/256, 256, 0, stream>>>(W1, W2, W1c, W2c);

    knn3_partial_kernel<<<BB * (NN/(PTH*QPT)) * NCH, PTH, 0, stream>>>(
        xyz1, packed, pd0, pd1, pd2, pi0, pi1, pi2);
    knn3_merge_kernel<<<MTOT/256, 256, 0, stream>>>(
        pd0, pd1, pd2, pi0, pi1, pi2, idx, w);

    // P2 = points2 @ W1[:,128:]^T   [B*S x 256], K=256, f16 out
    gemm_mfma_kernel<256, float, _Float16, false, false>
        <<<dim3((BB*SS)/64, C1/128), 256, 0, stream>>>(
        points2, D2, W1c + D1, D1 + D2, P2h, C1,
        nullptr, nullptr, nullptr, nullptr, nullptr);

    // temp = points1 @ W1[:,:128]^T   (plain GEMM, fp32 out, no fusion)
    gemm_mfma_kernel<128, float, float, false, false>
        <<<dim3(MTOT/64, C1/128), 256, 0, stream>>>(
        points1, D1, W1c, D1 + D2, tempf, C1,
        nullptr, nullptr, nullptr, nullptr, nullptr);

    // y1 = temp + interp(P2) + b1  (f16 out) + BN1 stats from fp32
    interp_stats_kernel<<<MTOT/32, 256, 0, stream>>>(
        tempf, P2h, idx, w, b1, y1h, sum1, sq1);

    finalize_kernel<<<1, 256, 0, stream>>>(sum1, sq1, g1, beta1, MTOT, C1, scale1, shift1);

    // out = relu(bn1(y1)) @ W2^T + b2;  fp32 out; fused BN2 stats
    gemm_mfma_kernel<256, _Float16, float, true, true>
        <<<dim3(MTOT/64, C2/128), 256, 0, stream>>>(
        y1h, C1, W2c, C1, out, C2,
        b2, scale1, shift1, sum2, sq2);

    finalize_kernel<<<1, 128, 0, stream>>>(sum2, sq2, g2, beta2, MTOT, C2, scale2, shift2);
    bnrelu_kernel<<<(MTOT*C2/4)/256, 256, 0, stream>>>(out, MTOT*C2/4, C2, scale2, shift2);
}

// Round 12
// 341.569 us; speedup vs baseline: 2.0442x; 2.0442x over previous
//
#include <hip/hip_runtime.h>
#include <hip/hip_bf16.h>
#include <math.h>

// Problem constants (fixed by setup_inputs)
#define BB 4
#define NN 16384
#define SS 4096
#define D1 128
#define D2 256
#define C1 256   // mlp[0]
#define C2 128   // mlp[1]
#define MTOT (BB*NN)   // 65536

// knn decomposition. R18: NO LDS — candidates read at wave-uniform global
// addresses -> s_load_dwordx16 (SMEM path, SGPR broadcast operands), removing
// the per-candidate ds_read_b128 LDS-pipe cost that R8-R11 could not move
// (153us invariant). R11 lesson: QPT=4 spilled (VGPR capped 32) -> QPT=2.
#define QPT 2              // queries per thread
#define SCH 256            // candidates per chunk
#define NCH (SS/SCH)       // 16 chunks
#define PTH 128            // threads per partial block
#define LB  4              // candidates per scalar load batch (16 dwords)

typedef _Float16 f16x8 __attribute__((ext_vector_type(8)));
typedef float f32x4  __attribute__((ext_vector_type(4)));
typedef int   i32x4  __attribute__((ext_vector_type(4)));

#define LPAD 40            // LDS row stride in fp16 elems (80B, 16B-aligned)

// ---------------------------------------------------------------------------
// Pack xyz2 into float4 {-2x, -2y, -2z, ||p||^2} (bit-exact vs reference:
// x(-2) is exact pow2 scaling, so (qq + cr2) + pw == (qq - 2*cr) + pw).
// ---------------------------------------------------------------------------
__global__ __launch_bounds__(256) void pack_kernel(
    const float* __restrict__ xyz2, float4* __restrict__ packed)
{
#pragma clang fp contract(off)
    int s = blockIdx.x * 256 + threadIdx.x;
    float px = xyz2[s*3+0], py = xyz2[s*3+1], pz = xyz2[s*3+2];
    float pp = (px*px + py*py) + pz*pz;
    packed[s] = make_float4(-2.0f*px, -2.0f*py, -2.0f*pz, pp);
}

// ---------------------------------------------------------------------------
// Convert W1, W2 to fp16 (RNE) once.
// ---------------------------------------------------------------------------
__global__ __launch_bounds__(256) void wcvt_kernel(
    const float* __restrict__ W1, const float* __restrict__ W2,
    _Float16* __restrict__ W1c, _Float16* __restrict__ W2c)
{
    int i = blockIdx.x * 256 + threadIdx.x;
    if (i < C1 * (D1 + D2)) W1c[i] = (_Float16)W1[i];
    if (i < C2 * C1)        W2c[i] = (_Float16)W2[i];
}

// ---------------------------------------------------------------------------
// 3-NN pass 1: exact fp32 distances (contract off), min/med3 distance chain +
// cndmask index chain, strict '<' with ascending candidate order (stable,
// == lax.top_k). HARD CONSTRAINT (R7): selection is discontinuous in the
// gathered features -> never approximate the distance or the comparison.
// R18: candidates fetched via uniform (scalar) global loads — no LDS stage,
// no barrier; p components become SGPR operands of the VALU ops.
// ---------------------------------------------------------------------------
__global__ __launch_bounds__(PTH, 8) void knn3_partial_kernel(
    const float* __restrict__ xyz1, const float4* __restrict__ packed,
    float* __restrict__ pd0, float* __restrict__ pd1, float* __restrict__ pd2,
    int* __restrict__ pi0, int* __restrict__ pi1, int* __restrict__ pi2)
{
#pragma clang fp contract(off)
    const int qblocks = NN / (PTH * QPT);            // 64
    const int b  = blockIdx.x / (qblocks * NCH);
    const int r  = blockIdx.x % (qblocks * NCH);
    const int qc = r / NCH;
    const int sc = r % NCH;

    // Wave-uniform candidate pointer (block-uniform -> scalar loads).
    const float4* __restrict__ src = packed + (size_t)b * SS + sc * SCH;

    float qx[QPT], qy[QPT], qz[QPT], qq[QPT];
    float e0[QPT], e1[QPT], e2[QPT];
    int   j0[QPT], j1[QPT], j2[QPT];
#pragma unroll
    for (int q = 0; q < QPT; ++q) {
        int n = qc * (PTH * QPT) + q * PTH + threadIdx.x;
        size_t m = (size_t)b * NN + n;
        qx[q] = xyz1[m*3+0]; qy[q] = xyz1[m*3+1]; qz[q] = xyz1[m*3+2];
        qq[q] = (qx[q]*qx[q] + qy[q]*qy[q]) + qz[q]*qz[q];
        e0[q] = 3.4e38f; e1[q] = 3.4e38f; e2[q] = 3.4e38f;
        j0[q] = 0; j1[q] = 0; j2[q] = 0;
    }

    auto proc = [&](float4 p, int s) {
#pragma clang fp contract(off)
#pragma unroll
        for (int q = 0; q < QPT; ++q) {
            float cr2 = (qx[q]*p.x + qy[q]*p.y) + qz[q]*p.z;   // == -2*cr exactly
            float d = (qq[q] + cr2) + p.w;
            d = fmaxf(d, 0.0f);
            bool c0 = d < e0[q], c1 = d < e1[q], c2 = d < e2[q];
            j2[q] = c1 ? j1[q] : (c2 ? s : j2[q]);
            j1[q] = c0 ? j0[q] : (c1 ? s : j1[q]);
            j0[q] = c0 ? s : j0[q];
            e2[q] = __builtin_amdgcn_fmed3f(e1[q], d, e2[q]);
            e1[q] = __builtin_amdgcn_fmed3f(e0[q], d, e1[q]);
            e0[q] = fminf(e0[q], d);
        }
    };

    for (int s = 0; s < SCH; s += LB) {
        float4 P0 = src[s+0];                        // uniform -> s_load_dwordx16
        float4 P1 = src[s+1];
        float4 P2v = src[s+2];
        float4 P3 = src[s+3];
        __builtin_amdgcn_sched_barrier(0);           // pin loads before bodies
        proc(P0, s+0);
        proc(P1, s+1);
        proc(P2v, s+2);
        proc(P3, s+3);
    }

#pragma unroll
    for (int q = 0; q < QPT; ++q) {
        int n = qc * (PTH * QPT) + q * PTH + threadIdx.x;
        size_t m = (size_t)b * NN + n;
        size_t o = (size_t)sc * MTOT + m;
        pd0[o] = e0[q]; pd1[o] = e1[q]; pd2[o] = e2[q];
        pi0[o] = sc*SCH + j0[q];
        pi1[o] = sc*SCH + j1[q];
        pi2[o] = sc*SCH + j2[q];
    }
}

// ---------------------------------------------------------------------------
// 3-NN pass 2: merge chunk triples (ascending chunk order, ascending j within
// chunk, strict '<') — identical scan order to a full ascending pass.
// SoA planes -> all loads lane-coalesced and mutually independent.
// ---------------------------------------------------------------------------
__global__ __launch_bounds__(256) void knn3_merge_kernel(
    const float* __restrict__ pd0, const float* __restrict__ pd1, const float* __restrict__ pd2,
    const int* __restrict__ pi0, const int* __restrict__ pi1, const int* __restrict__ pi2,
    int* __restrict__ idx_out, float* __restrict__ w_out)
{
#pragma clang fp contract(off)
    int m = blockIdx.x * 256 + threadIdx.x;
    int b = m / NN;

    float d0 = pd0[m], d1 = pd1[m], d2 = pd2[m];
    int   i0 = pi0[m], i1 = pi1[m], i2 = pi2[m];

#pragma unroll
    for (int c = 1; c < NCH; ++c) {
        size_t oc = (size_t)c * MTOT + m;
        float da = pd0[oc], db = pd1[oc], dc = pd2[oc];
        int   sa = pi0[oc], sb = pi1[oc], scv = pi2[oc];
        {
            float d = da; int s = sa;
            bool c0 = d < d0, c1 = d < d1, c2 = d < d2;
            d2 = c1 ? d1 : (c2 ? d : d2);  i2 = c1 ? i1 : (c2 ? s : i2);
            d1 = c0 ? d0 : (c1 ? d : d1);  i1 = c0 ? i0 : (c1 ? s : i1);
            d0 = c0 ? d : d0;              i0 = c0 ? s : i0;
        }
        {
            float d = db; int s = sb;
            bool c0 = d < d0, c1 = d < d1, c2 = d < d2;
            d2 = c1 ? d1 : (c2 ? d : d2);  i2 = c1 ? i1 : (c2 ? s : i2);
            d1 = c0 ? d0 : (c1 ? d : d1);  i1 = c0 ? i0 : (c1 ? s : i1);
            d0 = c0 ? d : d0;              i0 = c0 ? s : i0;
        }
        {
            float d = dc; int s = scv;
            bool c0 = d < d0, c1 = d < d1, c2 = d < d2;
            d2 = c1 ? d1 : (c2 ? d : d2);  i2 = c1 ? i1 : (c2 ? s : i2);
            d1 = c0 ? d0 : (c1 ? d : d1);  i1 = c0 ? i0 : (c1 ? s : i1);
            d0 = c0 ? d : d0;              i0 = c0 ? s : i0;
        }
    }
    float r0 = 1.0f / (d0 + 1e-8f);
    float r1 = 1.0f / (d1 + 1e-8f);
    float r2 = 1.0f / (d2 + 1e-8f);
    float inv = 1.0f / ((r0 + r1) + r2);
    idx_out[m*3+0] = b * SS + i0;
    idx_out[m*3+1] = b * SS + i1;
    idx_out[m*3+2] = b * SS + i2;
    w_out[m*3+0] = r0 * inv;
    w_out[m*3+1] = r1 * inv;
    w_out[m*3+2] = r2 * inv;
}

// ---------------------------------------------------------------------------
// fp16 MFMA GEMM, LDS double-buffered with ONE barrier per k-iter.
// C[M x N] = op(A[M x K]) @ W[N x K]^T (+ bias).
// Tile 64(M) x 128(N), 4 waves of 32x64, k-chunk 32 (16x16x32 f16 MFMA).
// ---------------------------------------------------------------------------
template<int K, typename AT, typename OT, bool BN_A, bool FUSE_STATS>
__global__ __launch_bounds__(256, 4) void gemm_mfma_kernel(
    const AT* __restrict__ A, int lda,
    const _Float16* __restrict__ W, int ldw,
    OT* __restrict__ C, int ldc,
    const float* __restrict__ bias,
    const float* __restrict__ scaleA, const float* __restrict__ shiftA,
    float* __restrict__ sumO, float* __restrict__ sqO)
{
    __shared__ _Float16 Ash[2][64 * LPAD];     // 2 x 5 KB
    __shared__ _Float16 Bsh[2][128 * LPAD];    // 2 x 10 KB

    const int tid = threadIdx.x;
    const int m0 = blockIdx.x * 64;
    const int n0 = blockIdx.y * 128;
    const int wave = tid >> 6, lane = tid & 63;
    const int ln = lane & 15, q4 = lane >> 4;
    const int wm = wave & 1, wn = wave >> 1;

    const int ar = tid >> 2, ak = (tid & 3) * 8;   // A staging: 64 rows x 32k
    const int br = tid >> 1, bk = (tid & 1) * 16;  // B staging: 128 rows x 32k

    f32x4 acc[2][4] = {};

    float  avF[8];      // used when AT == float
    f16x8  avH;         // used when AT == _Float16
    f16x8  bvA[2];

    {   // prologue prefetch k0 = 0
        if constexpr (__is_same(AT, float)) {
            const float* ap = A + (size_t)(m0 + ar) * lda + ak;
            *(float4*)&avF[0] = *(const float4*)ap;
            *(float4*)&avF[4] = *(const float4*)(ap + 4);
        } else {
            avH = *(const f16x8*)(A + (size_t)(m0 + ar) * lda + ak);
        }
        const _Float16* bp = W + (size_t)(n0 + br) * ldw + bk;
        bvA[0] = *(const f16x8*)bp;
        bvA[1] = *(const f16x8*)(bp + 8);
    }

    for (int k0 = 0; k0 < K; k0 += 32) {
        const int buf = (k0 >> 5) & 1;

        // ---- transform + store staged regs to LDS[buf] ----
        {
            float av[8];
            if constexpr (__is_same(AT, float)) {
#pragma unroll
                for (int i = 0; i < 8; ++i) av[i] = avF[i];
            } else {
#pragma unroll
                for (int i = 0; i < 8; ++i) av[i] = (float)avH[i];
            }
            if (BN_A) {
#pragma unroll
                for (int i = 0; i < 8; ++i) {
                    float sc = scaleA[k0 + ak + i];
                    float sh = shiftA[k0 + ak + i];
                    av[i] = fmaxf(av[i] * sc + sh, 0.0f);
                }
            }
            f16x8 vh;
#pragma unroll
            for (int i = 0; i < 8; ++i) vh[i] = (_Float16)av[i];
            *(f16x8*)&Ash[buf][ar * LPAD + ak] = vh;
            *(f16x8*)&Bsh[buf][br * LPAD + bk]     = bvA[0];
            *(f16x8*)&Bsh[buf][br * LPAD + bk + 8] = bvA[1];
        }
        __syncthreads();    // single barrier: writers of buf done; dbuf makes it safe

        // ---- issue next chunk's global loads (overlap with MFMA below) ----
        if (k0 + 32 < K) {
            if constexpr (__is_same(AT, float)) {
                const float* ap = A + (size_t)(m0 + ar) * lda + (k0 + 32) + ak;
                *(float4*)&avF[0] = *(const float4*)ap;
                *(float4*)&avF[4] = *(const float4*)(ap + 4);
            } else {
                avH = *(const f16x8*)(A + (size_t)(m0 + ar) * lda + (k0 + 32) + ak);
            }
            const _Float16* bp = W + (size_t)(n0 + br) * ldw + (k0 + 32) + bk;
            bvA[0] = *(const f16x8*)bp;
            bvA[1] = *(const f16x8*)(bp + 8);
        }

        // ---- fragments + MFMA ----
        f16x8 af[2];
#pragma unroll
        for (int mi = 0; mi < 2; ++mi) {
            int arow = wm * 32 + mi * 16 + ln;
            af[mi] = *(const f16x8*)&Ash[buf][arow * LPAD + q4 * 8];
        }
        f16x8 bf[4];
#pragma unroll
        for (int ni = 0; ni < 4; ++ni) {
            int brow = wn * 64 + ni * 16 + ln;
            bf[ni] = *(const f16x8*)&Bsh[buf][brow * LPAD + q4 * 8];
        }
#pragma unroll
        for (int mi = 0; mi < 2; ++mi)
#pragma unroll
            for (int ni = 0; ni < 4; ++ni)
                acc[mi][ni] = __builtin_amdgcn_mfma_f32_16x16x32_f16(af[mi], bf[ni], acc[mi][ni], 0, 0, 0);
    }

    // ---- epilogue ----  C/D layout: col = ln, row = q4*4 + r  (m89/m91)
#pragma unroll
    for (int ni = 0; ni < 4; ++ni) {
        int col = n0 + wn * 64 + ni * 16 + ln;
        float vb = bias ? bias[col] : 0.0f;
        float s = 0.0f, s2 = 0.0f;
#pragma unroll
        for (int mi = 0; mi < 2; ++mi) {
#pragma unroll
            for (int r = 0; r < 4; ++r) {
                int row_g = m0 + wm * 32 + mi * 16 + q4 * 4 + r;
                float v = acc[mi][ni][r] + vb;
                C[(size_t)row_g * ldc + col] = (OT)v;
                s += v; s2 += v * v;
            }
        }
        if (FUSE_STATS) {
            s  += __shfl_xor(s, 16);  s  += __shfl_xor(s, 32);
            s2 += __shfl_xor(s2, 16); s2 += __shfl_xor(s2, 32);
            if (q4 == 0) {
                atomicAdd(&sumO[col], s);
                atomicAdd(&sqO[col], s2);
            }
        }
    }
}

// ---------------------------------------------------------------------------
// Dedicated interp + bias + BN1-stats kernel.
// y1[m, :] = temp[m, :] + wa*P2[ia, :] + wb*P2[ib, :] + wc*P2[ic, :] + b1
// ---------------------------------------------------------------------------
__global__ __launch_bounds__(256, 8) void interp_stats_kernel(
    const float* __restrict__ temp,     // [MTOT x C1] fp32 gemm result
    const _Float16* __restrict__ P2,    // [BB*SS x C1] f16
    const int* __restrict__ idx3, const float* __restrict__ w3,
    const float* __restrict__ bias,
    _Float16* __restrict__ Y,           // [MTOT x C1] f16
    float* __restrict__ sumO, float* __restrict__ sqO)
{
    __shared__ float sred[2 * C1];      // 512 floats: [sum | sumsq]
    const int tid = threadIdx.x;
    const int sl  = tid & 31;           // col slice (8 cols)
    const int rg  = tid >> 5;           // 0..7
    const int m0  = blockIdx.x * 32;

    sred[tid] = 0.0f; sred[tid + 256] = 0.0f;
    __syncthreads();

    float bv[8];
    *(float4*)&bv[0] = *(const float4*)(bias + sl * 8);
    *(float4*)&bv[4] = *(const float4*)(bias + sl * 8 + 4);

    float sAcc[8]  = {0.f,0.f,0.f,0.f,0.f,0.f,0.f,0.f};
    float s2Acc[8] = {0.f,0.f,0.f,0.f,0.f,0.f,0.f,0.f};

#pragma unroll
    for (int rr = 0; rr < 4; ++rr) {
        const int row = m0 + rg * 4 + rr;
        const int*   ip = idx3 + (size_t)row * 3;
        const float* wp = w3   + (size_t)row * 3;
        int   ia = ip[0], ib = ip[1], ic = ip[2];
        float wa = wp[0], wb = wp[1], wc = wp[2];

        float av[8];
        const float* tp = temp + (size_t)row * C1 + sl * 8;
        *(float4*)&av[0] = *(const float4*)tp;
        *(float4*)&av[4] = *(const float4*)(tp + 4);
        f16x8 pa = *(const f16x8*)(P2 + (size_t)ia * C1 + sl * 8);
        f16x8 pb = *(const f16x8*)(P2 + (size_t)ib * C1 + sl * 8);
        f16x8 pc = *(const f16x8*)(P2 + (size_t)ic * C1 + sl * 8);

        f16x8 outv;
#pragma unroll
        for (int i = 0; i < 8; ++i) {
            float v = av[i];
            v += wa * (float)pa[i];
            v += wb * (float)pb[i];
            v += wc * (float)pc[i];
            v += bv[i];
            outv[i] = (_Float16)v;
            sAcc[i]  += v;
            s2Acc[i] += v * v;
        }
        *(f16x8*)(Y + (size_t)row * C1 + sl * 8) = outv;
    }

#pragma unroll
    for (int i = 0; i < 8; ++i) {
        atomicAdd(&sred[sl * 8 + i],       sAcc[i]);
        atomicAdd(&sred[256 + sl * 8 + i], s2Acc[i]);
    }
    __syncthreads();
    atomicAdd(&sumO[tid], sred[tid]);
    atomicAdd(&sqO[tid],  sred[tid + 256]);
}

// ---------------------------------------------------------------------------
__global__ void finalize_kernel(
    const float* __restrict__ sum, const float* __restrict__ sumsq,
    const float* __restrict__ g, const float* __restrict__ beta,
    int M, int C, float* __restrict__ scale, float* __restrict__ shift)
{
    int c = threadIdx.x;
    if (c >= C) return;
    float invM = 1.0f / (float)M;
    float mean = sum[c] * invM;
    float var = fmaxf(sumsq[c] * invM - mean * mean, 0.0f);
    float rstd = 1.0f / sqrtf(var + 1e-5f);
    float sc = g[c] * rstd;
    scale[c] = sc;
    shift[c] = beta[c] - mean * sc;
}

__global__ __launch_bounds__(256) void bnrelu_kernel(
    float* __restrict__ X, int total4, int C,
    const float* __restrict__ scale, const float* __restrict__ shift)
{
    int i = blockIdx.x * 256 + threadIdx.x;
    if (i >= total4) return;
    float4 v = ((const float4*)X)[i];
    int c = (i * 4) & (C - 1);      // C pow2, 4 | C -> no wrap within the 4
    v.x = fmaxf(v.x * scale[c+0] + shift[c+0], 0.0f);
    v.y = fmaxf(v.y * scale[c+1] + shift[c+1], 0.0f);
    v.z = fmaxf(v.z * scale[c+2] + shift[c+2], 0.0f);
    v.w = fmaxf(v.w * scale[c+3] + shift[c+3], 0.0f);
    ((float4*)X)[i] = v;
}

// ---------------------------------------------------------------------------
extern "C" void kernel_launch(void* const* d_in, const int* in_sizes, int n_in,
                              void* d_out, int out_size, void* d_ws, size_t ws_size,
                              hipStream_t stream) {
    const float* xyz1    = (const float*)d_in[0];
    const float* xyz2    = (const float*)d_in[1];
    const float* points1 = (const float*)d_in[2];
    const float* points2 = (const float*)d_in[3];
    const float* W1      = (const float*)d_in[4];
    const float* b1      = (const float*)d_in[5];
    const float* g1      = (const float*)d_in[6];
    const float* beta1   = (const float*)d_in[7];
    const float* W2      = (const float*)d_in[8];
    const float* b2      = (const float*)d_in[9];
    const float* g2      = (const float*)d_in[10];
    const float* beta2   = (const float*)d_in[11];
    float* out = (float*)d_out;

    // ws layout (byte offsets, 16B-aligned)
    char* ws = (char*)d_ws;
    size_t off = 0;
    int*   idx = (int*)(ws + off);            off += (size_t)MTOT*3*4;
    float* w   = (float*)(ws + off);          off += (size_t)MTOT*3*4;
    _Float16* P2h = (_Float16*)(ws + off);    off += (size_t)BB*SS*C1*2;    // 8 MB
    _Float16* y1h = (_Float16*)(ws + off);    off += (size_t)MTOT*C1*2;     // 32 MB
    float* stats = (float*)(ws + off);        off += 2048*4;
    float* sum1 = stats;            // 256
    float* sq1  = stats + 256;      // 256
    float* sum2 = stats + 512;      // 128
    float* sq2  = stats + 640;      // 128
    float* scale1 = stats + 768;    // 256
    float* shift1 = stats + 1024;   // 256
    float* scale2 = stats + 1280;   // 128
    float* shift2 = stats + 1408;   // 128
    float4* packed = (float4*)(ws + off);     off += (size_t)BB*SS*16;      // 1 MB
    _Float16* W1c = (_Float16*)(ws + off);    off += (size_t)C1*(D1+D2)*2;
    _Float16* W2c = (_Float16*)(ws + off);    off += (size_t)C2*C1*2;
    off = (off + 255) & ~(size_t)255;
    float* tempf = (float*)(ws + off);        off += (size_t)MTOT*C1*4;     // 64 MB
    // knn partials: 6 SoA planes of NCH*MTOT (25.2 MB total) alias the y1h
    // region (32 MB; y1h is written later, by interp_stats_kernel)
    float* pd0 = (float*)y1h;                 // NCH*MTOT floats (4.2 MB each)
    float* pd1 = pd0 + (size_t)NCH*MTOT;
    float* pd2 = pd1 + (size_t)NCH*MTOT;
    int*   pi0 = (int*)(pd2 + (size_t)NCH*MTOT);
    int*   pi1 = pi0 + (size_t)NCH*MTOT;
    int*   pi2 = pi1 + (size_t)NCH*MTOT;

    hipMemsetAsync(stats, 0, 768 * sizeof(float), stream);

    pack_kernel<<<(BB*SS)/256, 256, 0, stream>>>(xyz2, packed);
    wcvt_kernel<<<(C1*(D1+D2))/256, 256, 0, stream>>>(W1, W2, W1c, W2c);

    knn3_partial_kernel<<<BB * (NN/(PTH*QPT)) * NCH, PTH, 0, stream>>>(
        xyz1, packed, pd0, pd1, pd2, pi0, pi1, pi2);
    knn3_merge_kernel<<<MTOT/256, 256, 0, stream>>>(
        pd0, pd1, pd2, pi0, pi1, pi2, idx, w);

    // P2 = points2 @ W1[:,128:]^T   [B*S x 256], K=256, f16 out
    gemm_mfma_kernel<256, float, _Float16, false, false>
        <<<dim3((BB*SS)/64, C1/128), 256, 0, stream>>>(
        points2, D2, W1c + D1, D1 + D2, P2h, C1,
        nullptr, nullptr, nullptr, nullptr, nullptr);

    // temp = points1 @ W1[:,:128]^T   (plain GEMM, fp32 out, no fusion)
    gemm_mfma_kernel<128, float, float, false, false>
        <<<dim3(MTOT/64, C1/128), 256, 0, stream>>>(
        points1, D1, W1c, D1 + D2, tempf, C1,
        nullptr, nullptr, nullptr, nullptr, nullptr);

    // y1 = temp + interp(P2) + b1  (f16 out) + BN1 stats from fp32
    interp_stats_kernel<<<MTOT/32, 256, 0, stream>>>(
        tempf, P2h, idx, w, b1, y1h, sum1, sq1);

    finalize_kernel<<<1, 256, 0, stream>>>(sum1, sq1, g1, beta1, MTOT, C1, scale1, shift1);

    // out = relu(bn1(y1)) @ W2^T + b2;  fp32 out; fused BN2 stats
    gemm_mfma_kernel<256, _Float16, float, true, true>
        <<<dim3(MTOT/64, C2/128), 256, 0, stream>>>(
        y1h, C1, W2c, C1, out, C2,
        b2, scale1, shift1, sum2, sq2);

    finalize_kernel<<<1, 128, 0, stream>>>(sum2, sq2, g2, beta2, MTOT, C2, scale2, shift2);
    bnrelu_kernel<<<(MTOT*C2/4)/256, 256, 0, stream>>>(out, MTOT*C2/4, C2, scale2, shift2);
}

// Round 13
// 320.255 us; speedup vs baseline: 2.1803x; 1.0666x over previous
//
#include <hip/hip_runtime.h>
#include <hip/hip_bf16.h>
#include <math.h>

// Problem constants (fixed by setup_inputs)
#define BB 4
#define NN 16384
#define SS 4096
#define D1 128
#define D2 256
#define C1 256   // mlp[0]
#define C2 128   // mlp[1]
#define MTOT (BB*NN)   // 65536

// knn decomposition (R12 scalar-load engine, 148us proven; R19: fused into a
// mixed-grid super-kernel with the two independent GEMMs so their MFMA/memory
// work hides under knn's VALU time — m114: MFMA+VALU co-schedule, time=max).
#define QPT 2              // queries per thread
#define SCH 256            // candidates per chunk
#define NCH (SS/SCH)       // 16 chunks
#define LB  4              // candidates per scalar load batch (16 dwords)

#define KNN_BLOCKS  2048   // BB * NN/(256*QPT) * NCH = 4*32*16
#define P2_BLOCKS   512    // (BB*SS)/64 x C1/128 = 256 x 2
#define TEMP_BLOCKS 2048   // MTOT/64 x C1/128 = 1024 x 2
#define FAT_BLOCKS  4608   // 512 groups of (4 knn + 5 gemm)

typedef _Float16 f16x8 __attribute__((ext_vector_type(8)));
typedef float f32x4  __attribute__((ext_vector_type(4)));

#define LPAD 40            // LDS row stride in fp16 elems (80B, 16B-aligned)
#define SMEM_ELEMS (2*64*LPAD + 2*128*LPAD)   // 15360 f16 = 30 KB

// ---------------------------------------------------------------------------
// Pack xyz2 into float4 {-2x, -2y, -2z, ||p||^2} (bit-exact vs reference:
// x(-2) is exact pow2 scaling, so (qq + cr2) + pw == (qq - 2*cr) + pw).
// ---------------------------------------------------------------------------
__global__ __launch_bounds__(256) void pack_kernel(
    const float* __restrict__ xyz2, float4* __restrict__ packed)
{
#pragma clang fp contract(off)
    int s = blockIdx.x * 256 + threadIdx.x;
    float px = xyz2[s*3+0], py = xyz2[s*3+1], pz = xyz2[s*3+2];
    float pp = (px*px + py*py) + pz*pz;
    packed[s] = make_float4(-2.0f*px, -2.0f*py, -2.0f*pz, pp);
}

// ---------------------------------------------------------------------------
// Convert W1, W2 to fp16 (RNE) once.
// ---------------------------------------------------------------------------
__global__ __launch_bounds__(256) void wcvt_kernel(
    const float* __restrict__ W1, const float* __restrict__ W2,
    _Float16* __restrict__ W1c, _Float16* __restrict__ W2c)
{
    int i = blockIdx.x * 256 + threadIdx.x;
    if (i < C1 * (D1 + D2)) W1c[i] = (_Float16)W1[i];
    if (i < C2 * C1)        W2c[i] = (_Float16)W2[i];
}

// ---------------------------------------------------------------------------
// knn pass-1 body (R12 engine, 256-thread form): exact fp32 distances
// (contract off), min/med3 + cndmask chains, strict '<' ascending order
// (== lax.top_k). HARD CONSTRAINT (R7): never approximate the distance or
// the comparison. Candidates via wave-uniform scalar loads (no LDS).
// ---------------------------------------------------------------------------
__device__ __forceinline__ void knn_partial_body(
    int kb, int tid,
    const float* __restrict__ xyz1, const float4* __restrict__ packed,
    float* __restrict__ pd0, float* __restrict__ pd1, float* __restrict__ pd2,
    int* __restrict__ pi0, int* __restrict__ pi1, int* __restrict__ pi2)
{
#pragma clang fp contract(off)
    const int qblocks = NN / (256 * QPT);            // 32
    const int b  = kb / (qblocks * NCH);
    const int r  = kb % (qblocks * NCH);
    const int qc = r / NCH;
    const int sc = r % NCH;

    const float4* __restrict__ src = packed + (size_t)b * SS + sc * SCH;

    float qx[QPT], qy[QPT], qz[QPT], qq[QPT];
    float e0[QPT], e1[QPT], e2[QPT];
    int   j0[QPT], j1[QPT], j2[QPT];
#pragma unroll
    for (int q = 0; q < QPT; ++q) {
        int n = qc * (256 * QPT) + q * 256 + tid;
        size_t m = (size_t)b * NN + n;
        qx[q] = xyz1[m*3+0]; qy[q] = xyz1[m*3+1]; qz[q] = xyz1[m*3+2];
        qq[q] = (qx[q]*qx[q] + qy[q]*qy[q]) + qz[q]*qz[q];
        e0[q] = 3.4e38f; e1[q] = 3.4e38f; e2[q] = 3.4e38f;
        j0[q] = 0; j1[q] = 0; j2[q] = 0;
    }

    auto proc = [&](float4 p, int s) {
#pragma clang fp contract(off)
#pragma unroll
        for (int q = 0; q < QPT; ++q) {
            float cr2 = (qx[q]*p.x + qy[q]*p.y) + qz[q]*p.z;   // == -2*cr exactly
            float d = (qq[q] + cr2) + p.w;
            d = fmaxf(d, 0.0f);
            bool c0 = d < e0[q], c1 = d < e1[q], c2 = d < e2[q];
            j2[q] = c1 ? j1[q] : (c2 ? s : j2[q]);
            j1[q] = c0 ? j0[q] : (c1 ? s : j1[q]);
            j0[q] = c0 ? s : j0[q];
            e2[q] = __builtin_amdgcn_fmed3f(e1[q], d, e2[q]);
            e1[q] = __builtin_amdgcn_fmed3f(e0[q], d, e1[q]);
            e0[q] = fminf(e0[q], d);
        }
    };

    for (int s = 0; s < SCH; s += LB) {
        float4 P0 = src[s+0];                        // uniform -> s_load
        float4 P1 = src[s+1];
        float4 P2v = src[s+2];
        float4 P3 = src[s+3];
        __builtin_amdgcn_sched_barrier(0);           // pin loads before bodies
        proc(P0, s+0);
        proc(P1, s+1);
        proc(P2v, s+2);
        proc(P3, s+3);
    }

#pragma unroll
    for (int q = 0; q < QPT; ++q) {
        int n = qc * (256 * QPT) + q * 256 + tid;
        size_t m = (size_t)b * NN + n;
        size_t o = (size_t)sc * MTOT + m;
        pd0[o] = e0[q]; pd1[o] = e1[q]; pd2[o] = e2[q];
        pi0[o] = sc*SCH + j0[q];
        pi1[o] = sc*SCH + j1[q];
        pi2[o] = sc*SCH + j2[q];
    }
}

// ---------------------------------------------------------------------------
// Plain fp16 MFMA GEMM body (no fusion), LDS pool passed in (30 KB).
// C[M x N] = A[M x K] @ W[N x K]^T. Tile 64x128, 4 waves, k-chunk 32.
// ---------------------------------------------------------------------------
template<int K, typename AT, typename OT>
__device__ __forceinline__ void gemm_body(
    _Float16* __restrict__ smem, int bx, int by, int tid,
    const AT* __restrict__ A, int lda,
    const _Float16* __restrict__ W, int ldw,
    OT* __restrict__ C, int ldc)
{
#define ASHF(b_, i_) smem[(b_)*(64*LPAD) + (i_)]
#define BSHF(b_, i_) smem[2*64*LPAD + (b_)*(128*LPAD) + (i_)]
    const int m0 = bx * 64;
    const int n0 = by * 128;
    const int wave = tid >> 6, lane = tid & 63;
    const int ln = lane & 15, q4 = lane >> 4;
    const int wm = wave & 1, wn = wave >> 1;

    const int ar = tid >> 2, ak = (tid & 3) * 8;   // A staging: 64 rows x 32k
    const int br = tid >> 1, bk = (tid & 1) * 16;  // B staging: 128 rows x 32k

    f32x4 acc[2][4] = {};

    float  avF[8];
    f16x8  avH;
    f16x8  bvA[2];

    {   // prologue prefetch k0 = 0
        if constexpr (__is_same(AT, float)) {
            const float* ap = A + (size_t)(m0 + ar) * lda + ak;
            *(float4*)&avF[0] = *(const float4*)ap;
            *(float4*)&avF[4] = *(const float4*)(ap + 4);
        } else {
            avH = *(const f16x8*)(A + (size_t)(m0 + ar) * lda + ak);
        }
        const _Float16* bp = W + (size_t)(n0 + br) * ldw + bk;
        bvA[0] = *(const f16x8*)bp;
        bvA[1] = *(const f16x8*)(bp + 8);
    }

    for (int k0 = 0; k0 < K; k0 += 32) {
        const int buf = (k0 >> 5) & 1;
        {
            float av[8];
            if constexpr (__is_same(AT, float)) {
#pragma unroll
                for (int i = 0; i < 8; ++i) av[i] = avF[i];
            } else {
#pragma unroll
                for (int i = 0; i < 8; ++i) av[i] = (float)avH[i];
            }
            f16x8 vh;
#pragma unroll
            for (int i = 0; i < 8; ++i) vh[i] = (_Float16)av[i];
            *(f16x8*)&ASHF(buf, ar * LPAD + ak) = vh;
            *(f16x8*)&BSHF(buf, br * LPAD + bk)     = bvA[0];
            *(f16x8*)&BSHF(buf, br * LPAD + bk + 8) = bvA[1];
        }
        __syncthreads();

        if (k0 + 32 < K) {
            if constexpr (__is_same(AT, float)) {
                const float* ap = A + (size_t)(m0 + ar) * lda + (k0 + 32) + ak;
                *(float4*)&avF[0] = *(const float4*)ap;
                *(float4*)&avF[4] = *(const float4*)(ap + 4);
            } else {
                avH = *(const f16x8*)(A + (size_t)(m0 + ar) * lda + (k0 + 32) + ak);
            }
            const _Float16* bp = W + (size_t)(n0 + br) * ldw + (k0 + 32) + bk;
            bvA[0] = *(const f16x8*)bp;
            bvA[1] = *(const f16x8*)(bp + 8);
        }

        f16x8 af[2];
#pragma unroll
        for (int mi = 0; mi < 2; ++mi) {
            int arow = wm * 32 + mi * 16 + ln;
            af[mi] = *(const f16x8*)&ASHF(buf, arow * LPAD + q4 * 8);
        }
        f16x8 bf[4];
#pragma unroll
        for (int ni = 0; ni < 4; ++ni) {
            int brow = wn * 64 + ni * 16 + ln;
            bf[ni] = *(const f16x8*)&BSHF(buf, brow * LPAD + q4 * 8);
        }
#pragma unroll
        for (int mi = 0; mi < 2; ++mi)
#pragma unroll
            for (int ni = 0; ni < 4; ++ni)
                acc[mi][ni] = __builtin_amdgcn_mfma_f32_16x16x32_f16(af[mi], bf[ni], acc[mi][ni], 0, 0, 0);
    }

    // epilogue: C/D layout col = ln, row = q4*4 + r (m89/m91)
#pragma unroll
    for (int ni = 0; ni < 4; ++ni) {
        int col = n0 + wn * 64 + ni * 16 + ln;
#pragma unroll
        for (int mi = 0; mi < 2; ++mi) {
#pragma unroll
            for (int r = 0; r < 4; ++r) {
                int row_g = m0 + wm * 32 + mi * 16 + q4 * 4 + r;
                C[(size_t)row_g * ldc + col] = (OT)acc[mi][ni][r];
            }
        }
    }
#undef ASHF
#undef BSHF
}

// ---------------------------------------------------------------------------
// R19 super-kernel: mixed grid of knn-partial blocks (VALU-bound) and the two
// independent GEMMs (MFMA/memory-bound). blockIdx%9: 0..3 -> knn, 4..8 -> gemm.
// Pipes overlap on-CU (m114) -> GEMM time hides under knn time.
// ---------------------------------------------------------------------------
__global__ __launch_bounds__(256, 4) void fused_knn_gemm_kernel(
    const float* __restrict__ xyz1, const float4* __restrict__ packed,
    float* __restrict__ pd0, float* __restrict__ pd1, float* __restrict__ pd2,
    int* __restrict__ pi0, int* __restrict__ pi1, int* __restrict__ pi2,
    const float* __restrict__ points2, const float* __restrict__ points1,
    const _Float16* __restrict__ W1c, _Float16* __restrict__ P2h,
    float* __restrict__ tempf)
{
    __shared__ _Float16 smem[SMEM_ELEMS];            // 30 KB (gemm branches)
    const int g = blockIdx.x;
    const int grp = g / 9, l9 = g % 9;
    const int tid = threadIdx.x;

    if (l9 < 4) {
        knn_partial_body(grp * 4 + l9, tid, xyz1, packed,
                         pd0, pd1, pd2, pi0, pi1, pi2);
    } else {
        int gi = grp * 5 + (l9 - 4);                 // 0..2559
        if (gi < P2_BLOCKS) {
            // P2 = points2 @ W1[:,128:]^T  [16384 x 256], K=256, f16 out
            gemm_body<256, float, _Float16>(smem, gi & 255, gi >> 8, tid,
                points2, D2, W1c + D1, D1 + D2, P2h, C1);
        } else {
            gi -= P2_BLOCKS;                          // 0..2047
            // temp = points1 @ W1[:,:128]^T  [65536 x 256], K=128, fp32 out
            gemm_body<128, float, float>(smem, gi & 1023, gi >> 10, tid,
                points1, D1, W1c, D1 + D2, tempf, C1);
        }
    }
}

// ---------------------------------------------------------------------------
// 3-NN pass 2: merge chunk triples (ascending chunk order, strict '<').
// ---------------------------------------------------------------------------
__global__ __launch_bounds__(256) void knn3_merge_kernel(
    const float* __restrict__ pd0, const float* __restrict__ pd1, const float* __restrict__ pd2,
    const int* __restrict__ pi0, const int* __restrict__ pi1, const int* __restrict__ pi2,
    int* __restrict__ idx_out, float* __restrict__ w_out)
{
#pragma clang fp contract(off)
    int m = blockIdx.x * 256 + threadIdx.x;
    int b = m / NN;

    float d0 = pd0[m], d1 = pd1[m], d2 = pd2[m];
    int   i0 = pi0[m], i1 = pi1[m], i2 = pi2[m];

#pragma unroll
    for (int c = 1; c < NCH; ++c) {
        size_t oc = (size_t)c * MTOT + m;
        float da = pd0[oc], db = pd1[oc], dc = pd2[oc];
        int   sa = pi0[oc], sb = pi1[oc], scv = pi2[oc];
        {
            float d = da; int s = sa;
            bool c0 = d < d0, c1 = d < d1, c2 = d < d2;
            d2 = c1 ? d1 : (c2 ? d : d2);  i2 = c1 ? i1 : (c2 ? s : i2);
            d1 = c0 ? d0 : (c1 ? d : d1);  i1 = c0 ? i0 : (c1 ? s : i1);
            d0 = c0 ? d : d0;              i0 = c0 ? s : i0;
        }
        {
            float d = db; int s = sb;
            bool c0 = d < d0, c1 = d < d1, c2 = d < d2;
            d2 = c1 ? d1 : (c2 ? d : d2);  i2 = c1 ? i1 : (c2 ? s : i2);
            d1 = c0 ? d0 : (c1 ? d : d1);  i1 = c0 ? i0 : (c1 ? s : i1);
            d0 = c0 ? d : d0;              i0 = c0 ? s : i0;
        }
        {
            float d = dc; int s = scv;
            bool c0 = d < d0, c1 = d < d1, c2 = d < d2;
            d2 = c1 ? d1 : (c2 ? d : d2);  i2 = c1 ? i1 : (c2 ? s : i2);
            d1 = c0 ? d0 : (c1 ? d : d1);  i1 = c0 ? i0 : (c1 ? s : i1);
            d0 = c0 ? d : d0;              i0 = c0 ? s : i0;
        }
    }
    float r0 = 1.0f / (d0 + 1e-8f);
    float r1 = 1.0f / (d1 + 1e-8f);
    float r2 = 1.0f / (d2 + 1e-8f);
    float inv = 1.0f / ((r0 + r1) + r2);
    idx_out[m*3+0] = b * SS + i0;
    idx_out[m*3+1] = b * SS + i1;
    idx_out[m*3+2] = b * SS + i2;
    w_out[m*3+0] = r0 * inv;
    w_out[m*3+1] = r1 * inv;
    w_out[m*3+2] = r2 * inv;
}

// ---------------------------------------------------------------------------
// Fused-stats fp16 MFMA GEMM (bn2 path): BN+ReLU on A, stats atomics out.
// ---------------------------------------------------------------------------
template<int K>
__global__ __launch_bounds__(256, 4) void gemm_bn2_kernel(
    const _Float16* __restrict__ A, int lda,
    const _Float16* __restrict__ W, int ldw,
    float* __restrict__ C, int ldc,
    const float* __restrict__ bias,
    const float* __restrict__ scaleA, const float* __restrict__ shiftA,
    float* __restrict__ sumO, float* __restrict__ sqO)
{
    __shared__ _Float16 Ash[2][64 * LPAD];
    __shared__ _Float16 Bsh[2][128 * LPAD];

    const int tid = threadIdx.x;
    const int m0 = blockIdx.x * 64;
    const int n0 = blockIdx.y * 128;
    const int wave = tid >> 6, lane = tid & 63;
    const int ln = lane & 15, q4 = lane >> 4;
    const int wm = wave & 1, wn = wave >> 1;

    const int ar = tid >> 2, ak = (tid & 3) * 8;
    const int br = tid >> 1, bk = (tid & 1) * 16;

    f32x4 acc[2][4] = {};
    f16x8  avH;
    f16x8  bvA[2];

    {
        avH = *(const f16x8*)(A + (size_t)(m0 + ar) * lda + ak);
        const _Float16* bp = W + (size_t)(n0 + br) * ldw + bk;
        bvA[0] = *(const f16x8*)bp;
        bvA[1] = *(const f16x8*)(bp + 8);
    }

    for (int k0 = 0; k0 < K; k0 += 32) {
        const int buf = (k0 >> 5) & 1;
        {
            float av[8];
#pragma unroll
            for (int i = 0; i < 8; ++i) av[i] = (float)avH[i];
#pragma unroll
            for (int i = 0; i < 8; ++i) {
                float sc = scaleA[k0 + ak + i];
                float sh = shiftA[k0 + ak + i];
                av[i] = fmaxf(av[i] * sc + sh, 0.0f);
            }
            f16x8 vh;
#pragma unroll
            for (int i = 0; i < 8; ++i) vh[i] = (_Float16)av[i];
            *(f16x8*)&Ash[buf][ar * LPAD + ak] = vh;
            *(f16x8*)&Bsh[buf][br * LPAD + bk]     = bvA[0];
            *(f16x8*)&Bsh[buf][br * LPAD + bk + 8] = bvA[1];
        }
        __syncthreads();

        if (k0 + 32 < K) {
            avH = *(const f16x8*)(A + (size_t)(m0 + ar) * lda + (k0 + 32) + ak);
            const _Float16* bp = W + (size_t)(n0 + br) * ldw + (k0 + 32) + bk;
            bvA[0] = *(const f16x8*)bp;
            bvA[1] = *(const f16x8*)(bp + 8);
        }

        f16x8 af[2];
#pragma unroll
        for (int mi = 0; mi < 2; ++mi) {
            int arow = wm * 32 + mi * 16 + ln;
            af[mi] = *(const f16x8*)&Ash[buf][arow * LPAD + q4 * 8];
        }
        f16x8 bf[4];
#pragma unroll
        for (int ni = 0; ni < 4; ++ni) {
            int brow = wn * 64 + ni * 16 + ln;
            bf[ni] = *(const f16x8*)&Bsh[buf][brow * LPAD + q4 * 8];
        }
#pragma unroll
        for (int mi = 0; mi < 2; ++mi)
#pragma unroll
            for (int ni = 0; ni < 4; ++ni)
                acc[mi][ni] = __builtin_amdgcn_mfma_f32_16x16x32_f16(af[mi], bf[ni], acc[mi][ni], 0, 0, 0);
    }

#pragma unroll
    for (int ni = 0; ni < 4; ++ni) {
        int col = n0 + wn * 64 + ni * 16 + ln;
        float vb = bias[col];
        float s = 0.0f, s2 = 0.0f;
#pragma unroll
        for (int mi = 0; mi < 2; ++mi) {
#pragma unroll
            for (int r = 0; r < 4; ++r) {
                int row_g = m0 + wm * 32 + mi * 16 + q4 * 4 + r;
                float v = acc[mi][ni][r] + vb;
                C[(size_t)row_g * ldc + col] = v;
                s += v; s2 += v * v;
            }
        }
        s  += __shfl_xor(s, 16);  s  += __shfl_xor(s, 32);
        s2 += __shfl_xor(s2, 16); s2 += __shfl_xor(s2, 32);
        if (q4 == 0) {
            atomicAdd(&sumO[col], s);
            atomicAdd(&sqO[col], s2);
        }
    }
}

// ---------------------------------------------------------------------------
// Dedicated interp + bias + BN1-stats kernel.
// y1[m, :] = temp[m, :] + wa*P2[ia, :] + wb*P2[ib, :] + wc*P2[ic, :] + b1
// ---------------------------------------------------------------------------
__global__ __launch_bounds__(256, 8) void interp_stats_kernel(
    const float* __restrict__ temp,     // [MTOT x C1] fp32 gemm result
    const _Float16* __restrict__ P2,    // [BB*SS x C1] f16
    const int* __restrict__ idx3, const float* __restrict__ w3,
    const float* __restrict__ bias,
    _Float16* __restrict__ Y,           // [MTOT x C1] f16
    float* __restrict__ sumO, float* __restrict__ sqO)
{
    __shared__ float sred[2 * C1];      // 512 floats: [sum | sumsq]
    const int tid = threadIdx.x;
    const int sl  = tid & 31;           // col slice (8 cols)
    const int rg  = tid >> 5;           // 0..7
    const int m0  = blockIdx.x * 32;

    sred[tid] = 0.0f; sred[tid + 256] = 0.0f;
    __syncthreads();

    float bv[8];
    *(float4*)&bv[0] = *(const float4*)(bias + sl * 8);
    *(float4*)&bv[4] = *(const float4*)(bias + sl * 8 + 4);

    float sAcc[8]  = {0.f,0.f,0.f,0.f,0.f,0.f,0.f,0.f};
    float s2Acc[8] = {0.f,0.f,0.f,0.f,0.f,0.f,0.f,0.f};

#pragma unroll
    for (int rr = 0; rr < 4; ++rr) {
        const int row = m0 + rg * 4 + rr;
        const int*   ip = idx3 + (size_t)row * 3;
        const float* wp = w3   + (size_t)row * 3;
        int   ia = ip[0], ib = ip[1], ic = ip[2];
        float wa = wp[0], wb = wp[1], wc = wp[2];

        float av[8];
        const float* tp = temp + (size_t)row * C1 + sl * 8;
        *(float4*)&av[0] = *(const float4*)tp;
        *(float4*)&av[4] = *(const float4*)(tp + 4);
        f16x8 pa = *(const f16x8*)(P2 + (size_t)ia * C1 + sl * 8);
        f16x8 pb = *(const f16x8*)(P2 + (size_t)ib * C1 + sl * 8);
        f16x8 pc = *(const f16x8*)(P2 + (size_t)ic * C1 + sl * 8);

        f16x8 outv;
#pragma unroll
        for (int i = 0; i < 8; ++i) {
            float v = av[i];
            v += wa * (float)pa[i];
            v += wb * (float)pb[i];
            v += wc * (float)pc[i];
            v += bv[i];
            outv[i] = (_Float16)v;
            sAcc[i]  += v;
            s2Acc[i] += v * v;
        }
        *(f16x8*)(Y + (size_t)row * C1 + sl * 8) = outv;
    }

#pragma unroll
    for (int i = 0; i < 8; ++i) {
        atomicAdd(&sred[sl * 8 + i],       sAcc[i]);
        atomicAdd(&sred[256 + sl * 8 + i], s2Acc[i]);
    }
    __syncthreads();
    atomicAdd(&sumO[tid], sred[tid]);
    atomicAdd(&sqO[tid],  sred[tid + 256]);
}

// ---------------------------------------------------------------------------
__global__ void finalize_kernel(
    const float* __restrict__ sum, const float* __restrict__ sumsq,
    const float* __restrict__ g, const float* __restrict__ beta,
    int M, int C, float* __restrict__ scale, float* __restrict__ shift)
{
    int c = threadIdx.x;
    if (c >= C) return;
    float invM = 1.0f / (float)M;
    float mean = sum[c] * invM;
    float var = fmaxf(sumsq[c] * invM - mean * mean, 0.0f);
    float rstd = 1.0f / sqrtf(var + 1e-5f);
    float sc = g[c] * rstd;
    scale[c] = sc;
    shift[c] = beta[c] - mean * sc;
}

__global__ __launch_bounds__(256) void bnrelu_kernel(
    float* __restrict__ X, int total4, int C,
    const float* __restrict__ scale, const float* __restrict__ shift)
{
    int i = blockIdx.x * 256 + threadIdx.x;
    if (i >= total4) return;
    float4 v = ((const float4*)X)[i];
    int c = (i * 4) & (C - 1);      // C pow2, 4 | C -> no wrap within the 4
    v.x = fmaxf(v.x * scale[c+0] + shift[c+0], 0.0f);
    v.y = fmaxf(v.y * scale[c+1] + shift[c+1], 0.0f);
    v.z = fmaxf(v.z * scale[c+2] + shift[c+2], 0.0f);
    v.w = fmaxf(v.w * scale[c+3] + shift[c+3], 0.0f);
    ((float4*)X)[i] = v;
}

// ---------------------------------------------------------------------------
extern "C" void kernel_launch(void* const* d_in, const int* in_sizes, int n_in,
                              void* d_out, int out_size, void* d_ws, size_t ws_size,
                              hipStream_t stream) {
    const float* xyz1    = (const float*)d_in[0];
    const float* xyz2    = (const float*)d_in[1];
    const float* points1 = (const float*)d_in[2];
    const float* points2 = (const float*)d_in[3];
    const float* W1      = (const float*)d_in[4];
    const float* b1      = (const float*)d_in[5];
    const float* g1      = (const float*)d_in[6];
    const float* beta1   = (const float*)d_in[7];
    const float* W2      = (const float*)d_in[8];
    const float* b2      = (const float*)d_in[9];
    const float* g2      = (const float*)d_in[10];
    const float* beta2   = (const float*)d_in[11];
    float* out = (float*)d_out;

    // ws layout (byte offsets, 16B-aligned)
    char* ws = (char*)d_ws;
    size_t off = 0;
    int*   idx = (int*)(ws + off);            off += (size_t)MTOT*3*4;
    float* w   = (float*)(ws + off);          off += (size_t)MTOT*3*4;
    _Float16* P2h = (_Float16*)(ws + off);    off += (size_t)BB*SS*C1*2;    // 8 MB
    _Float16* y1h = (_Float16*)(ws + off);    off += (size_t)MTOT*C1*2;     // 32 MB
    float* stats = (float*)(ws + off);        off += 2048*4;
    float* sum1 = stats;            // 256
    float* sq1  = stats + 256;      // 256
    float* sum2 = stats + 512;      // 128
    float* sq2  = stats + 640;      // 128
    float* scale1 = stats + 768;    // 256
    float* shift1 = stats + 1024;   // 256
    float* scale2 = stats + 1280;   // 128
    float* shift2 = stats + 1408;   // 128
    float4* packed = (float4*)(ws + off);     off += (size_t)BB*SS*16;      // 1 MB
    _Float16* W1c = (_Float16*)(ws + off);    off += (size_t)C1*(D1+D2)*2;
    _Float16* W2c = (_Float16*)(ws + off);    off += (size_t)C2*C1*2;
    off = (off + 255) & ~(size_t)255;
    float* tempf = (float*)(ws + off);        off += (size_t)MTOT*C1*4;     // 64 MB
    // knn partials: 6 SoA planes of NCH*MTOT (25.2 MB total) alias the y1h
    // region (32 MB; y1h is written later, by interp_stats_kernel)
    float* pd0 = (float*)y1h;                 // NCH*MTOT floats (4.2 MB each)
    float* pd1 = pd0 + (size_t)NCH*MTOT;
    float* pd2 = pd1 + (size_t)NCH*MTOT;
    int*   pi0 = (int*)(pd2 + (size_t)NCH*MTOT);
    int*   pi1 = pi0 + (size_t)NCH*MTOT;
    int*   pi2 = pi1 + (size_t)NCH*MTOT;

    hipMemsetAsync(stats, 0, 768 * sizeof(float), stream);

    pack_kernel<<<(BB*SS)/256, 256, 0, stream>>>(xyz2, packed);
    wcvt_kernel<<<(C1*(D1+D2))/256, 256, 0, stream>>>(W1, W2, W1c, W2c);

    // R19 super-kernel: knn partial + P2 GEMM + temp GEMM, mixed grid
    fused_knn_gemm_kernel<<<FAT_BLOCKS, 256, 0, stream>>>(
        xyz1, packed, pd0, pd1, pd2, pi0, pi1, pi2,
        points2, points1, W1c, P2h, tempf);

    knn3_merge_kernel<<<MTOT/256, 256, 0, stream>>>(
        pd0, pd1, pd2, pi0, pi1, pi2, idx, w);

    // y1 = temp + interp(P2) + b1  (f16 out) + BN1 stats from fp32
    interp_stats_kernel<<<MTOT/32, 256, 0, stream>>>(
        tempf, P2h, idx, w, b1, y1h, sum1, sq1);

    finalize_kernel<<<1, 256, 0, stream>>>(sum1, sq1, g1, beta1, MTOT, C1, scale1, shift1);

    // out = relu(bn1(y1)) @ W2^T + b2;  fp32 out; fused BN2 stats
    gemm_bn2_kernel<256><<<dim3(MTOT/64, C2/128), 256, 0, stream>>>(
        y1h, C1, W2c, C1, out, C2,
        b2, scale1, shift1, sum2, sq2);

    finalize_kernel<<<1, 128, 0, stream>>>(sum2, sq2, g2, beta2, MTOT, C2, scale2, shift2);
    bnrelu_kernel<<<(MTOT*C2/4)/256, 256, 0, stream>>>(out, MTOT*C2/4, C2, scale2, shift2);
}

// Round 14
// 318.275 us; speedup vs baseline: 2.1938x; 1.0062x over previous
//
#include <hip/hip_runtime.h>
#include <hip/hip_bf16.h>
#include <math.h>

// Problem constants (fixed by setup_inputs)
#define BB 4
#define NN 16384
#define SS 4096
#define D1 128
#define D2 256
#define C1 256   // mlp[0]
#define C2 128   // mlp[1]
#define MTOT (BB*NN)   // 65536

// knn decomposition (R12 scalar-load engine; R19 mixed-grid fusion with the
// two independent GEMMs proved +21us win: MFMA hides under knn VALU, m114).
// R20: f16 temp (halves temp traffic), finalize folded into consumers.
#define QPT 2              // queries per thread
#define SCH 256            // candidates per chunk
#define NCH (SS/SCH)       // 16 chunks
#define LB  4              // candidates per scalar load batch (16 dwords)

#define KNN_BLOCKS  2048   // BB * NN/(256*QPT) * NCH = 4*32*16
#define P2_BLOCKS   512    // (BB*SS)/64 x C1/128 = 256 x 2
#define TEMP_BLOCKS 2048   // MTOT/64 x C1/128 = 1024 x 2
#define FAT_BLOCKS  4608   // 512 groups of (4 knn + 5 gemm)

typedef _Float16 f16x8 __attribute__((ext_vector_type(8)));
typedef float f32x4  __attribute__((ext_vector_type(4)));

#define LPAD 40            // LDS row stride in fp16 elems (80B, 16B-aligned)
#define SMEM_ELEMS (2*64*LPAD + 2*128*LPAD)   // 15360 f16 = 30 KB

// ---------------------------------------------------------------------------
// Pack xyz2 into float4 {-2x, -2y, -2z, ||p||^2} (bit-exact vs reference:
// x(-2) is exact pow2 scaling, so (qq + cr2) + pw == (qq - 2*cr) + pw).
// ---------------------------------------------------------------------------
__global__ __launch_bounds__(256) void pack_kernel(
    const float* __restrict__ xyz2, float4* __restrict__ packed)
{
#pragma clang fp contract(off)
    int s = blockIdx.x * 256 + threadIdx.x;
    float px = xyz2[s*3+0], py = xyz2[s*3+1], pz = xyz2[s*3+2];
    float pp = (px*px + py*py) + pz*pz;
    packed[s] = make_float4(-2.0f*px, -2.0f*py, -2.0f*pz, pp);
}

// ---------------------------------------------------------------------------
// Convert W1, W2 to fp16 (RNE) once.
// ---------------------------------------------------------------------------
__global__ __launch_bounds__(256) void wcvt_kernel(
    const float* __restrict__ W1, const float* __restrict__ W2,
    _Float16* __restrict__ W1c, _Float16* __restrict__ W2c)
{
    int i = blockIdx.x * 256 + threadIdx.x;
    if (i < C1 * (D1 + D2)) W1c[i] = (_Float16)W1[i];
    if (i < C2 * C1)        W2c[i] = (_Float16)W2[i];
}

// ---------------------------------------------------------------------------
// knn pass-1 body (R12 engine): exact fp32 distances (contract off),
// min/med3 + cndmask chains, strict '<' ascending order (== lax.top_k).
// HARD CONSTRAINT (R7): never approximate the distance or the comparison.
// ---------------------------------------------------------------------------
__device__ __forceinline__ void knn_partial_body(
    int kb, int tid,
    const float* __restrict__ xyz1, const float4* __restrict__ packed,
    float* __restrict__ pd0, float* __restrict__ pd1, float* __restrict__ pd2,
    int* __restrict__ pi0, int* __restrict__ pi1, int* __restrict__ pi2)
{
#pragma clang fp contract(off)
    const int qblocks = NN / (256 * QPT);            // 32
    const int b  = kb / (qblocks * NCH);
    const int r  = kb % (qblocks * NCH);
    const int qc = r / NCH;
    const int sc = r % NCH;

    const float4* __restrict__ src = packed + (size_t)b * SS + sc * SCH;

    float qx[QPT], qy[QPT], qz[QPT], qq[QPT];
    float e0[QPT], e1[QPT], e2[QPT];
    int   j0[QPT], j1[QPT], j2[QPT];
#pragma unroll
    for (int q = 0; q < QPT; ++q) {
        int n = qc * (256 * QPT) + q * 256 + tid;
        size_t m = (size_t)b * NN + n;
        qx[q] = xyz1[m*3+0]; qy[q] = xyz1[m*3+1]; qz[q] = xyz1[m*3+2];
        qq[q] = (qx[q]*qx[q] + qy[q]*qy[q]) + qz[q]*qz[q];
        e0[q] = 3.4e38f; e1[q] = 3.4e38f; e2[q] = 3.4e38f;
        j0[q] = 0; j1[q] = 0; j2[q] = 0;
    }

    auto proc = [&](float4 p, int s) {
#pragma clang fp contract(off)
#pragma unroll
        for (int q = 0; q < QPT; ++q) {
            float cr2 = (qx[q]*p.x + qy[q]*p.y) + qz[q]*p.z;   // == -2*cr exactly
            float d = (qq[q] + cr2) + p.w;
            d = fmaxf(d, 0.0f);
            bool c0 = d < e0[q], c1 = d < e1[q], c2 = d < e2[q];
            j2[q] = c1 ? j1[q] : (c2 ? s : j2[q]);
            j1[q] = c0 ? j0[q] : (c1 ? s : j1[q]);
            j0[q] = c0 ? s : j0[q];
            e2[q] = __builtin_amdgcn_fmed3f(e1[q], d, e2[q]);
            e1[q] = __builtin_amdgcn_fmed3f(e0[q], d, e1[q]);
            e0[q] = fminf(e0[q], d);
        }
    };

    for (int s = 0; s < SCH; s += LB) {
        float4 P0 = src[s+0];                        // uniform -> s_load
        float4 P1 = src[s+1];
        float4 P2v = src[s+2];
        float4 P3 = src[s+3];
        __builtin_amdgcn_sched_barrier(0);           // pin loads before bodies
        proc(P0, s+0);
        proc(P1, s+1);
        proc(P2v, s+2);
        proc(P3, s+3);
    }

#pragma unroll
    for (int q = 0; q < QPT; ++q) {
        int n = qc * (256 * QPT) + q * 256 + tid;
        size_t m = (size_t)b * NN + n;
        size_t o = (size_t)sc * MTOT + m;
        pd0[o] = e0[q]; pd1[o] = e1[q]; pd2[o] = e2[q];
        pi0[o] = sc*SCH + j0[q];
        pi1[o] = sc*SCH + j1[q];
        pi2[o] = sc*SCH + j2[q];
    }
}

// ---------------------------------------------------------------------------
// Plain fp16 MFMA GEMM body (no fusion), LDS pool passed in (30 KB).
// C[M x N] = A[M x K] @ W[N x K]^T. Tile 64x128, 4 waves, k-chunk 32.
// ---------------------------------------------------------------------------
template<int K, typename AT, typename OT>
__device__ __forceinline__ void gemm_body(
    _Float16* __restrict__ smem, int bx, int by, int tid,
    const AT* __restrict__ A, int lda,
    const _Float16* __restrict__ W, int ldw,
    OT* __restrict__ C, int ldc)
{
#define ASHF(b_, i_) smem[(b_)*(64*LPAD) + (i_)]
#define BSHF(b_, i_) smem[2*64*LPAD + (b_)*(128*LPAD) + (i_)]
    const int m0 = bx * 64;
    const int n0 = by * 128;
    const int wave = tid >> 6, lane = tid & 63;
    const int ln = lane & 15, q4 = lane >> 4;
    const int wm = wave & 1, wn = wave >> 1;

    const int ar = tid >> 2, ak = (tid & 3) * 8;   // A staging: 64 rows x 32k
    const int br = tid >> 1, bk = (tid & 1) * 16;  // B staging: 128 rows x 32k

    f32x4 acc[2][4] = {};

    float  avF[8];
    f16x8  avH;
    f16x8  bvA[2];

    {   // prologue prefetch k0 = 0
        if constexpr (__is_same(AT, float)) {
            const float* ap = A + (size_t)(m0 + ar) * lda + ak;
            *(float4*)&avF[0] = *(const float4*)ap;
            *(float4*)&avF[4] = *(const float4*)(ap + 4);
        } else {
            avH = *(const f16x8*)(A + (size_t)(m0 + ar) * lda + ak);
        }
        const _Float16* bp = W + (size_t)(n0 + br) * ldw + bk;
        bvA[0] = *(const f16x8*)bp;
        bvA[1] = *(const f16x8*)(bp + 8);
    }

    for (int k0 = 0; k0 < K; k0 += 32) {
        const int buf = (k0 >> 5) & 1;
        {
            float av[8];
            if constexpr (__is_same(AT, float)) {
#pragma unroll
                for (int i = 0; i < 8; ++i) av[i] = avF[i];
            } else {
#pragma unroll
                for (int i = 0; i < 8; ++i) av[i] = (float)avH[i];
            }
            f16x8 vh;
#pragma unroll
            for (int i = 0; i < 8; ++i) vh[i] = (_Float16)av[i];
            *(f16x8*)&ASHF(buf, ar * LPAD + ak) = vh;
            *(f16x8*)&BSHF(buf, br * LPAD + bk)     = bvA[0];
            *(f16x8*)&BSHF(buf, br * LPAD + bk + 8) = bvA[1];
        }
        __syncthreads();

        if (k0 + 32 < K) {
            if constexpr (__is_same(AT, float)) {
                const float* ap = A + (size_t)(m0 + ar) * lda + (k0 + 32) + ak;
                *(float4*)&avF[0] = *(const float4*)ap;
                *(float4*)&avF[4] = *(const float4*)(ap + 4);
            } else {
                avH = *(const f16x8*)(A + (size_t)(m0 + ar) * lda + (k0 + 32) + ak);
            }
            const _Float16* bp = W + (size_t)(n0 + br) * ldw + (k0 + 32) + bk;
            bvA[0] = *(const f16x8*)bp;
            bvA[1] = *(const f16x8*)(bp + 8);
        }

        f16x8 af[2];
#pragma unroll
        for (int mi = 0; mi < 2; ++mi) {
            int arow = wm * 32 + mi * 16 + ln;
            af[mi] = *(const f16x8*)&ASHF(buf, arow * LPAD + q4 * 8);
        }
        f16x8 bf[4];
#pragma unroll
        for (int ni = 0; ni < 4; ++ni) {
            int brow = wn * 64 + ni * 16 + ln;
            bf[ni] = *(const f16x8*)&BSHF(buf, brow * LPAD + q4 * 8);
        }
#pragma unroll
        for (int mi = 0; mi < 2; ++mi)
#pragma unroll
            for (int ni = 0; ni < 4; ++ni)
                acc[mi][ni] = __builtin_amdgcn_mfma_f32_16x16x32_f16(af[mi], bf[ni], acc[mi][ni], 0, 0, 0);
    }

    // epilogue: C/D layout col = ln, row = q4*4 + r (m89/m91)
#pragma unroll
    for (int ni = 0; ni < 4; ++ni) {
        int col = n0 + wn * 64 + ni * 16 + ln;
#pragma unroll
        for (int mi = 0; mi < 2; ++mi) {
#pragma unroll
            for (int r = 0; r < 4; ++r) {
                int row_g = m0 + wm * 32 + mi * 16 + q4 * 4 + r;
                C[(size_t)row_g * ldc + col] = (OT)acc[mi][ni][r];
            }
        }
    }
#undef ASHF
#undef BSHF
}

// ---------------------------------------------------------------------------
// R19 super-kernel: mixed grid of knn-partial blocks (VALU-bound) and the two
// independent GEMMs (MFMA/memory-bound). blockIdx%9: 0..3 -> knn, 4..8 -> gemm.
// R20: temp output is f16 (halves temp traffic; +<=5e-4 abs rounding, two
// orders below the 0.03125 absmax).
// ---------------------------------------------------------------------------
__global__ __launch_bounds__(256, 4) void fused_knn_gemm_kernel(
    const float* __restrict__ xyz1, const float4* __restrict__ packed,
    float* __restrict__ pd0, float* __restrict__ pd1, float* __restrict__ pd2,
    int* __restrict__ pi0, int* __restrict__ pi1, int* __restrict__ pi2,
    const float* __restrict__ points2, const float* __restrict__ points1,
    const _Float16* __restrict__ W1c, _Float16* __restrict__ P2h,
    _Float16* __restrict__ temph)
{
    __shared__ _Float16 smem[SMEM_ELEMS];            // 30 KB (gemm branches)
    const int g = blockIdx.x;
    const int grp = g / 9, l9 = g % 9;
    const int tid = threadIdx.x;

    if (l9 < 4) {
        knn_partial_body(grp * 4 + l9, tid, xyz1, packed,
                         pd0, pd1, pd2, pi0, pi1, pi2);
    } else {
        int gi = grp * 5 + (l9 - 4);                 // 0..2559
        if (gi < P2_BLOCKS) {
            // P2 = points2 @ W1[:,128:]^T  [16384 x 256], K=256, f16 out
            gemm_body<256, float, _Float16>(smem, gi & 255, gi >> 8, tid,
                points2, D2, W1c + D1, D1 + D2, P2h, C1);
        } else {
            gi -= P2_BLOCKS;                          // 0..2047
            // temp = points1 @ W1[:,:128]^T  [65536 x 256], K=128, f16 out
            gemm_body<128, float, _Float16>(smem, gi & 1023, gi >> 10, tid,
                points1, D1, W1c, D1 + D2, temph, C1);
        }
    }
}

// ---------------------------------------------------------------------------
// 3-NN pass 2: merge chunk triples (ascending chunk order, strict '<').
// ---------------------------------------------------------------------------
__global__ __launch_bounds__(256) void knn3_merge_kernel(
    const float* __restrict__ pd0, const float* __restrict__ pd1, const float* __restrict__ pd2,
    const int* __restrict__ pi0, const int* __restrict__ pi1, const int* __restrict__ pi2,
    int* __restrict__ idx_out, float* __restrict__ w_out)
{
#pragma clang fp contract(off)
    int m = blockIdx.x * 256 + threadIdx.x;
    int b = m / NN;

    float d0 = pd0[m], d1 = pd1[m], d2 = pd2[m];
    int   i0 = pi0[m], i1 = pi1[m], i2 = pi2[m];

#pragma unroll
    for (int c = 1; c < NCH; ++c) {
        size_t oc = (size_t)c * MTOT + m;
        float da = pd0[oc], db = pd1[oc], dc = pd2[oc];
        int   sa = pi0[oc], sb = pi1[oc], scv = pi2[oc];
        {
            float d = da; int s = sa;
            bool c0 = d < d0, c1 = d < d1, c2 = d < d2;
            d2 = c1 ? d1 : (c2 ? d : d2);  i2 = c1 ? i1 : (c2 ? s : i2);
            d1 = c0 ? d0 : (c1 ? d : d1);  i1 = c0 ? i0 : (c1 ? s : i1);
            d0 = c0 ? d : d0;              i0 = c0 ? s : i0;
        }
        {
            float d = db; int s = sb;
            bool c0 = d < d0, c1 = d < d1, c2 = d < d2;
            d2 = c1 ? d1 : (c2 ? d : d2);  i2 = c1 ? i1 : (c2 ? s : i2);
            d1 = c0 ? d0 : (c1 ? d : d1);  i1 = c0 ? i0 : (c1 ? s : i1);
            d0 = c0 ? d : d0;              i0 = c0 ? s : i0;
        }
        {
            float d = dc; int s = scv;
            bool c0 = d < d0, c1 = d < d1, c2 = d < d2;
            d2 = c1 ? d1 : (c2 ? d : d2);  i2 = c1 ? i1 : (c2 ? s : i2);
            d1 = c0 ? d0 : (c1 ? d : d1);  i1 = c0 ? i0 : (c1 ? s : i1);
            d0 = c0 ? d : d0;              i0 = c0 ? s : i0;
        }
    }
    float r0 = 1.0f / (d0 + 1e-8f);
    float r1 = 1.0f / (d1 + 1e-8f);
    float r2 = 1.0f / (d2 + 1e-8f);
    float inv = 1.0f / ((r0 + r1) + r2);
    idx_out[m*3+0] = b * SS + i0;
    idx_out[m*3+1] = b * SS + i1;
    idx_out[m*3+2] = b * SS + i2;
    w_out[m*3+0] = r0 * inv;
    w_out[m*3+1] = r1 * inv;
    w_out[m*3+2] = r2 * inv;
}

// ---------------------------------------------------------------------------
// Fused-stats fp16 MFMA GEMM (bn2 path): computes scale1/shift1 in-block
// from BN1 sums (R20: finalize folded in), BN+ReLU on A, stats atomics out.
// ---------------------------------------------------------------------------
template<int K>
__global__ __launch_bounds__(256, 4) void gemm_bn2_kernel(
    const _Float16* __restrict__ A, int lda,
    const _Float16* __restrict__ W, int ldw,
    float* __restrict__ C, int ldc,
    const float* __restrict__ bias,
    const float* __restrict__ sum1, const float* __restrict__ sq1,
    const float* __restrict__ g1, const float* __restrict__ beta1,
    float* __restrict__ sumO, float* __restrict__ sqO)
{
    __shared__ _Float16 Ash[2][64 * LPAD];
    __shared__ _Float16 Bsh[2][128 * LPAD];
    __shared__ float scA[C1], shA[C1];     // 2 KB: in-block finalize1

    const int tid = threadIdx.x;
    {   // scale1/shift1 from BN1 sums (256 channels, one per thread)
        float invM = 1.0f / (float)MTOT;
        float mean = sum1[tid] * invM;
        float var = fmaxf(sq1[tid] * invM - mean * mean, 0.0f);
        float rstd = 1.0f / sqrtf(var + 1e-5f);
        float sc = g1[tid] * rstd;
        scA[tid] = sc;
        shA[tid] = beta1[tid] - mean * sc;
    }
    __syncthreads();

    const int m0 = blockIdx.x * 64;
    const int n0 = blockIdx.y * 128;
    const int wave = tid >> 6, lane = tid & 63;
    const int ln = lane & 15, q4 = lane >> 4;
    const int wm = wave & 1, wn = wave >> 1;

    const int ar = tid >> 2, ak = (tid & 3) * 8;
    const int br = tid >> 1, bk = (tid & 1) * 16;

    f32x4 acc[2][4] = {};
    f16x8  avH;
    f16x8  bvA[2];

    {
        avH = *(const f16x8*)(A + (size_t)(m0 + ar) * lda + ak);
        const _Float16* bp = W + (size_t)(n0 + br) * ldw + bk;
        bvA[0] = *(const f16x8*)bp;
        bvA[1] = *(const f16x8*)(bp + 8);
    }

    for (int k0 = 0; k0 < K; k0 += 32) {
        const int buf = (k0 >> 5) & 1;
        {
            float av[8];
#pragma unroll
            for (int i = 0; i < 8; ++i) av[i] = (float)avH[i];
#pragma unroll
            for (int i = 0; i < 8; ++i) {
                float sc = scA[k0 + ak + i];
                float sh = shA[k0 + ak + i];
                av[i] = fmaxf(av[i] * sc + sh, 0.0f);
            }
            f16x8 vh;
#pragma unroll
            for (int i = 0; i < 8; ++i) vh[i] = (_Float16)av[i];
            *(f16x8*)&Ash[buf][ar * LPAD + ak] = vh;
            *(f16x8*)&Bsh[buf][br * LPAD + bk]     = bvA[0];
            *(f16x8*)&Bsh[buf][br * LPAD + bk + 8] = bvA[1];
        }
        __syncthreads();

        if (k0 + 32 < K) {
            avH = *(const f16x8*)(A + (size_t)(m0 + ar) * lda + (k0 + 32) + ak);
            const _Float16* bp = W + (size_t)(n0 + br) * ldw + (k0 + 32) + bk;
            bvA[0] = *(const f16x8*)bp;
            bvA[1] = *(const f16x8*)(bp + 8);
        }

        f16x8 af[2];
#pragma unroll
        for (int mi = 0; mi < 2; ++mi) {
            int arow = wm * 32 + mi * 16 + ln;
            af[mi] = *(const f16x8*)&Ash[buf][arow * LPAD + q4 * 8];
        }
        f16x8 bf[4];
#pragma unroll
        for (int ni = 0; ni < 4; ++ni) {
            int brow = wn * 64 + ni * 16 + ln;
            bf[ni] = *(const f16x8*)&Bsh[buf][brow * LPAD + q4 * 8];
        }
#pragma unroll
        for (int mi = 0; mi < 2; ++mi)
#pragma unroll
            for (int ni = 0; ni < 4; ++ni)
                acc[mi][ni] = __builtin_amdgcn_mfma_f32_16x16x32_f16(af[mi], bf[ni], acc[mi][ni], 0, 0, 0);
    }

#pragma unroll
    for (int ni = 0; ni < 4; ++ni) {
        int col = n0 + wn * 64 + ni * 16 + ln;
        float vb = bias[col];
        float s = 0.0f, s2 = 0.0f;
#pragma unroll
        for (int mi = 0; mi < 2; ++mi) {
#pragma unroll
            for (int r = 0; r < 4; ++r) {
                int row_g = m0 + wm * 32 + mi * 16 + q4 * 4 + r;
                float v = acc[mi][ni][r] + vb;
                C[(size_t)row_g * ldc + col] = v;
                s += v; s2 += v * v;
            }
        }
        s  += __shfl_xor(s, 16);  s  += __shfl_xor(s, 32);
        s2 += __shfl_xor(s2, 16); s2 += __shfl_xor(s2, 32);
        if (q4 == 0) {
            atomicAdd(&sumO[col], s);
            atomicAdd(&sqO[col], s2);
        }
    }
}

// ---------------------------------------------------------------------------
// Dedicated interp + bias + BN1-stats kernel (R20: temp is f16).
// y1[m, :] = temp[m, :] + wa*P2[ia, :] + wb*P2[ib, :] + wc*P2[ic, :] + b1
// ---------------------------------------------------------------------------
__global__ __launch_bounds__(256, 8) void interp_stats_kernel(
    const _Float16* __restrict__ temp,  // [MTOT x C1] f16 gemm result
    const _Float16* __restrict__ P2,    // [BB*SS x C1] f16
    const int* __restrict__ idx3, const float* __restrict__ w3,
    const float* __restrict__ bias,
    _Float16* __restrict__ Y,           // [MTOT x C1] f16
    float* __restrict__ sumO, float* __restrict__ sqO)
{
    __shared__ float sred[2 * C1];      // 512 floats: [sum | sumsq]
    const int tid = threadIdx.x;
    const int sl  = tid & 31;           // col slice (8 cols)
    const int rg  = tid >> 5;           // 0..7
    const int m0  = blockIdx.x * 32;

    sred[tid] = 0.0f; sred[tid + 256] = 0.0f;
    __syncthreads();

    float bv[8];
    *(float4*)&bv[0] = *(const float4*)(bias + sl * 8);
    *(float4*)&bv[4] = *(const float4*)(bias + sl * 8 + 4);

    float sAcc[8]  = {0.f,0.f,0.f,0.f,0.f,0.f,0.f,0.f};
    float s2Acc[8] = {0.f,0.f,0.f,0.f,0.f,0.f,0.f,0.f};

#pragma unroll
    for (int rr = 0; rr < 4; ++rr) {
        const int row = m0 + rg * 4 + rr;
        const int*   ip = idx3 + (size_t)row * 3;
        const float* wp = w3   + (size_t)row * 3;
        int   ia = ip[0], ib = ip[1], ic = ip[2];
        float wa = wp[0], wb = wp[1], wc = wp[2];

        f16x8 av = *(const f16x8*)(temp + (size_t)row * C1 + sl * 8);
        f16x8 pa = *(const f16x8*)(P2 + (size_t)ia * C1 + sl * 8);
        f16x8 pb = *(const f16x8*)(P2 + (size_t)ib * C1 + sl * 8);
        f16x8 pc = *(const f16x8*)(P2 + (size_t)ic * C1 + sl * 8);

        f16x8 outv;
#pragma unroll
        for (int i = 0; i < 8; ++i) {
            float v = (float)av[i];
            v += wa * (float)pa[i];
            v += wb * (float)pb[i];
            v += wc * (float)pc[i];
            v += bv[i];
            outv[i] = (_Float16)v;
            sAcc[i]  += v;
            s2Acc[i] += v * v;
        }
        *(f16x8*)(Y + (size_t)row * C1 + sl * 8) = outv;
    }

#pragma unroll
    for (int i = 0; i < 8; ++i) {
        atomicAdd(&sred[sl * 8 + i],       sAcc[i]);
        atomicAdd(&sred[256 + sl * 8 + i], s2Acc[i]);
    }
    __syncthreads();
    atomicAdd(&sumO[tid], sred[tid]);
    atomicAdd(&sqO[tid],  sred[tid + 256]);
}

// ---------------------------------------------------------------------------
// bnrelu with in-block finalize2 (R20): scale2/shift2 from BN2 sums per block.
// ---------------------------------------------------------------------------
__global__ __launch_bounds__(256) void bnrelu_kernel(
    float* __restrict__ X, int total4, int C,
    const float* __restrict__ sum2, const float* __restrict__ sq2,
    const float* __restrict__ g2, const float* __restrict__ beta2)
{
    __shared__ float sc2[C2], sh2[C2];     // 1 KB
    const int tid = threadIdx.x;
    if (tid < C2) {
        float invM = 1.0f / (float)MTOT;
        float mean = sum2[tid] * invM;
        float var = fmaxf(sq2[tid] * invM - mean * mean, 0.0f);
        float rstd = 1.0f / sqrtf(var + 1e-5f);
        float sc = g2[tid] * rstd;
        sc2[tid] = sc;
        sh2[tid] = beta2[tid] - mean * sc;
    }
    __syncthreads();

    int i = blockIdx.x * 256 + tid;
    if (i >= total4) return;
    float4 v = ((const float4*)X)[i];
    int c = (i * 4) & (C - 1);      // C pow2, 4 | C -> no wrap within the 4
    v.x = fmaxf(v.x * sc2[c+0] + sh2[c+0], 0.0f);
    v.y = fmaxf(v.y * sc2[c+1] + sh2[c+1], 0.0f);
    v.z = fmaxf(v.z * sc2[c+2] + sh2[c+2], 0.0f);
    v.w = fmaxf(v.w * sc2[c+3] + sh2[c+3], 0.0f);
    ((float4*)X)[i] = v;
}

// ---------------------------------------------------------------------------
extern "C" void kernel_launch(void* const* d_in, const int* in_sizes, int n_in,
                              void* d_out, int out_size, void* d_ws, size_t ws_size,
                              hipStream_t stream) {
    const float* xyz1    = (const float*)d_in[0];
    const float* xyz2    = (const float*)d_in[1];
    const float* points1 = (const float*)d_in[2];
    const float* points2 = (const float*)d_in[3];
    const float* W1      = (const float*)d_in[4];
    const float* b1      = (const float*)d_in[5];
    const float* g1      = (const float*)d_in[6];
    const float* beta1   = (const float*)d_in[7];
    const float* W2      = (const float*)d_in[8];
    const float* b2      = (const float*)d_in[9];
    const float* g2      = (const float*)d_in[10];
    const float* beta2   = (const float*)d_in[11];
    float* out = (float*)d_out;

    // ws layout (byte offsets, 16B-aligned)
    char* ws = (char*)d_ws;
    size_t off = 0;
    int*   idx = (int*)(ws + off);            off += (size_t)MTOT*3*4;
    float* w   = (float*)(ws + off);          off += (size_t)MTOT*3*4;
    _Float16* P2h = (_Float16*)(ws + off);    off += (size_t)BB*SS*C1*2;    // 8 MB
    _Float16* y1h = (_Float16*)(ws + off);    off += (size_t)MTOT*C1*2;     // 32 MB
    float* stats = (float*)(ws + off);        off += 2048*4;
    float* sum1 = stats;            // 256
    float* sq1  = stats + 256;      // 256
    float* sum2 = stats + 512;      // 128
    float* sq2  = stats + 640;      // 128
    float4* packed = (float4*)(ws + off);     off += (size_t)BB*SS*16;      // 1 MB
    _Float16* W1c = (_Float16*)(ws + off);    off += (size_t)C1*(D1+D2)*2;
    _Float16* W2c = (_Float16*)(ws + off);    off += (size_t)C2*C1*2;
    off = (off + 255) & ~(size_t)255;
    _Float16* temph = (_Float16*)(ws + off);  off += (size_t)MTOT*C1*2;     // 32 MB
    // knn partials: 6 SoA planes of NCH*MTOT (25.2 MB total) alias the y1h
    // region (32 MB; y1h is written later, by interp_stats_kernel)
    float* pd0 = (float*)y1h;                 // NCH*MTOT floats (4.2 MB each)
    float* pd1 = pd0 + (size_t)NCH*MTOT;
    float* pd2 = pd1 + (size_t)NCH*MTOT;
    int*   pi0 = (int*)(pd2 + (size_t)NCH*MTOT);
    int*   pi1 = pi0 + (size_t)NCH*MTOT;
    int*   pi2 = pi1 + (size_t)NCH*MTOT;

    hipMemsetAsync(stats, 0, 768 * sizeof(float), stream);

    pack_kernel<<<(BB*SS)/256, 256, 0, stream>>>(xyz2, packed);
    wcvt_kernel<<<(C1*(D1+D2))/256, 256, 0, stream>>>(W1, W2, W1c, W2c);

    // R19 super-kernel: knn partial + P2 GEMM + temp GEMM, mixed grid
    fused_knn_gemm_kernel<<<FAT_BLOCKS, 256, 0, stream>>>(
        xyz1, packed, pd0, pd1, pd2, pi0, pi1, pi2,
        points2, points1, W1c, P2h, temph);

    knn3_merge_kernel<<<MTOT/256, 256, 0, stream>>>(
        pd0, pd1, pd2, pi0, pi1, pi2, idx, w);

    // y1 = temp + interp(P2) + b1  (f16 out) + BN1 stats from fp32
    interp_stats_kernel<<<MTOT/32, 256, 0, stream>>>(
        temph, P2h, idx, w, b1, y1h, sum1, sq1);

    // out = relu(bn1(y1)) @ W2^T + b2;  fp32 out; in-block finalize1 + BN2 stats
    gemm_bn2_kernel<256><<<dim3(MTOT/64, C2/128), 256, 0, stream>>>(
        y1h, C1, W2c, C1, out, C2,
        b2, sum1, sq1, g1, beta1, sum2, sq2);

    // bnrelu with in-block finalize2
    bnrelu_kernel<<<(MTOT*C2/4)/256, 256, 0, stream>>>(
        out, MTOT*C2/4, C2, sum2, sq2, g2, beta2);
}

// Round 15
// 317.163 us; speedup vs baseline: 2.2015x; 1.0035x over previous
//
#include <hip/hip_runtime.h>
#include <hip/hip_bf16.h>
#include <math.h>

// Problem constants (fixed by setup_inputs)
#define BB 4
#define NN 16384
#define SS 4096
#define D1 128
#define D2 256
#define C1 256   // mlp[0]
#define C2 128   // mlp[1]
#define MTOT (BB*NN)   // 65536

// knn decomposition (R12 scalar-load engine; R19 mixed-grid fusion; R20 f16
// temp + folded finalizes; R21: merge fused into interp, pack+wcvt fused).
#define QPT 2              // queries per thread
#define SCH 256            // candidates per chunk
#define NCH (SS/SCH)       // 16 chunks
#define LB  4              // candidates per scalar load batch (16 dwords)

#define P2_BLOCKS   512    // (BB*SS)/64 x C1/128 = 256 x 2
#define FAT_BLOCKS  4608   // 512 groups of (4 knn + 5 gemm)

typedef _Float16 f16x8 __attribute__((ext_vector_type(8)));
typedef float f32x4  __attribute__((ext_vector_type(4)));

#define LPAD 40            // LDS row stride in fp16 elems (80B, 16B-aligned)
#define SMEM_ELEMS (2*64*LPAD + 2*128*LPAD)   // 15360 f16 = 30 KB

// ---------------------------------------------------------------------------
// R21 setup: pack xyz2 -> {-2x,-2y,-2z,||p||^2} (bit-exact: pow2 scaling)
// and convert W1,W2 to f16, one launch.
// ---------------------------------------------------------------------------
__global__ __launch_bounds__(256) void setup_kernel(
    const float* __restrict__ xyz2, float4* __restrict__ packed,
    const float* __restrict__ W1, const float* __restrict__ W2,
    _Float16* __restrict__ W1c, _Float16* __restrict__ W2c)
{
#pragma clang fp contract(off)
    int i = blockIdx.x * 256 + threadIdx.x;
    if (i < BB * SS) {
        float px = xyz2[(size_t)i*3+0], py = xyz2[(size_t)i*3+1], pz = xyz2[(size_t)i*3+2];
        float pp = (px*px + py*py) + pz*pz;
        packed[i] = make_float4(-2.0f*px, -2.0f*py, -2.0f*pz, pp);
    }
    int j = i - BB * SS;
    if (j >= 0 && j < C1 * (D1 + D2)) W1c[j] = (_Float16)W1[j];
    if (j >= 0 && j < C2 * C1)        W2c[j] = (_Float16)W2[j];
}

// ---------------------------------------------------------------------------
// knn pass-1 body (R12 engine): exact fp32 distances (contract off),
// min/med3 + cndmask chains, strict '<' ascending order (== lax.top_k).
// HARD CONSTRAINT (R7): never approximate the distance or the comparison.
// ---------------------------------------------------------------------------
__device__ __forceinline__ void knn_partial_body(
    int kb, int tid,
    const float* __restrict__ xyz1, const float4* __restrict__ packed,
    float* __restrict__ pd0, float* __restrict__ pd1, float* __restrict__ pd2,
    int* __restrict__ pi0, int* __restrict__ pi1, int* __restrict__ pi2)
{
#pragma clang fp contract(off)
    const int qblocks = NN / (256 * QPT);            // 32
    const int b  = kb / (qblocks * NCH);
    const int r  = kb % (qblocks * NCH);
    const int qc = r / NCH;
    const int sc = r % NCH;

    const float4* __restrict__ src = packed + (size_t)b * SS + sc * SCH;

    float qx[QPT], qy[QPT], qz[QPT], qq[QPT];
    float e0[QPT], e1[QPT], e2[QPT];
    int   j0[QPT], j1[QPT], j2[QPT];
#pragma unroll
    for (int q = 0; q < QPT; ++q) {
        int n = qc * (256 * QPT) + q * 256 + tid;
        size_t m = (size_t)b * NN + n;
        qx[q] = xyz1[m*3+0]; qy[q] = xyz1[m*3+1]; qz[q] = xyz1[m*3+2];
        qq[q] = (qx[q]*qx[q] + qy[q]*qy[q]) + qz[q]*qz[q];
        e0[q] = 3.4e38f; e1[q] = 3.4e38f; e2[q] = 3.4e38f;
        j0[q] = 0; j1[q] = 0; j2[q] = 0;
    }

    auto proc = [&](float4 p, int s) {
#pragma clang fp contract(off)
#pragma unroll
        for (int q = 0; q < QPT; ++q) {
            float cr2 = (qx[q]*p.x + qy[q]*p.y) + qz[q]*p.z;   // == -2*cr exactly
            float d = (qq[q] + cr2) + p.w;
            d = fmaxf(d, 0.0f);
            bool c0 = d < e0[q], c1 = d < e1[q], c2 = d < e2[q];
            j2[q] = c1 ? j1[q] : (c2 ? s : j2[q]);
            j1[q] = c0 ? j0[q] : (c1 ? s : j1[q]);
            j0[q] = c0 ? s : j0[q];
            e2[q] = __builtin_amdgcn_fmed3f(e1[q], d, e2[q]);
            e1[q] = __builtin_amdgcn_fmed3f(e0[q], d, e1[q]);
            e0[q] = fminf(e0[q], d);
        }
    };

    for (int s = 0; s < SCH; s += LB) {
        float4 P0 = src[s+0];                        // uniform -> s_load
        float4 P1 = src[s+1];
        float4 P2v = src[s+2];
        float4 P3 = src[s+3];
        __builtin_amdgcn_sched_barrier(0);           // pin loads before bodies
        proc(P0, s+0);
        proc(P1, s+1);
        proc(P2v, s+2);
        proc(P3, s+3);
    }

#pragma unroll
    for (int q = 0; q < QPT; ++q) {
        int n = qc * (256 * QPT) + q * 256 + tid;
        size_t m = (size_t)b * NN + n;
        size_t o = (size_t)sc * MTOT + m;
        pd0[o] = e0[q]; pd1[o] = e1[q]; pd2[o] = e2[q];
        pi0[o] = sc*SCH + j0[q];
        pi1[o] = sc*SCH + j1[q];
        pi2[o] = sc*SCH + j2[q];
    }
}

// ---------------------------------------------------------------------------
// Plain fp16 MFMA GEMM body (no fusion), LDS pool passed in (30 KB).
// C[M x N] = A[M x K] @ W[N x K]^T. Tile 64x128, 4 waves, k-chunk 32.
// ---------------------------------------------------------------------------
template<int K, typename AT, typename OT>
__device__ __forceinline__ void gemm_body(
    _Float16* __restrict__ smem, int bx, int by, int tid,
    const AT* __restrict__ A, int lda,
    const _Float16* __restrict__ W, int ldw,
    OT* __restrict__ C, int ldc)
{
#define ASHF(b_, i_) smem[(b_)*(64*LPAD) + (i_)]
#define BSHF(b_, i_) smem[2*64*LPAD + (b_)*(128*LPAD) + (i_)]
    const int m0 = bx * 64;
    const int n0 = by * 128;
    const int wave = tid >> 6, lane = tid & 63;
    const int ln = lane & 15, q4 = lane >> 4;
    const int wm = wave & 1, wn = wave >> 1;

    const int ar = tid >> 2, ak = (tid & 3) * 8;   // A staging: 64 rows x 32k
    const int br = tid >> 1, bk = (tid & 1) * 16;  // B staging: 128 rows x 32k

    f32x4 acc[2][4] = {};

    float  avF[8];
    f16x8  avH;
    f16x8  bvA[2];

    {   // prologue prefetch k0 = 0
        if constexpr (__is_same(AT, float)) {
            const float* ap = A + (size_t)(m0 + ar) * lda + ak;
            *(float4*)&avF[0] = *(const float4*)ap;
            *(float4*)&avF[4] = *(const float4*)(ap + 4);
        } else {
            avH = *(const f16x8*)(A + (size_t)(m0 + ar) * lda + ak);
        }
        const _Float16* bp = W + (size_t)(n0 + br) * ldw + bk;
        bvA[0] = *(const f16x8*)bp;
        bvA[1] = *(const f16x8*)(bp + 8);
    }

    for (int k0 = 0; k0 < K; k0 += 32) {
        const int buf = (k0 >> 5) & 1;
        {
            float av[8];
            if constexpr (__is_same(AT, float)) {
#pragma unroll
                for (int i = 0; i < 8; ++i) av[i] = avF[i];
            } else {
#pragma unroll
                for (int i = 0; i < 8; ++i) av[i] = (float)avH[i];
            }
            f16x8 vh;
#pragma unroll
            for (int i = 0; i < 8; ++i) vh[i] = (_Float16)av[i];
            *(f16x8*)&ASHF(buf, ar * LPAD + ak) = vh;
            *(f16x8*)&BSHF(buf, br * LPAD + bk)     = bvA[0];
            *(f16x8*)&BSHF(buf, br * LPAD + bk + 8) = bvA[1];
        }
        __syncthreads();

        if (k0 + 32 < K) {
            if constexpr (__is_same(AT, float)) {
                const float* ap = A + (size_t)(m0 + ar) * lda + (k0 + 32) + ak;
                *(float4*)&avF[0] = *(const float4*)ap;
                *(float4*)&avF[4] = *(const float4*)(ap + 4);
            } else {
                avH = *(const f16x8*)(A + (size_t)(m0 + ar) * lda + (k0 + 32) + ak);
            }
            const _Float16* bp = W + (size_t)(n0 + br) * ldw + (k0 + 32) + bk;
            bvA[0] = *(const f16x8*)bp;
            bvA[1] = *(const f16x8*)(bp + 8);
        }

        f16x8 af[2];
#pragma unroll
        for (int mi = 0; mi < 2; ++mi) {
            int arow = wm * 32 + mi * 16 + ln;
            af[mi] = *(const f16x8*)&ASHF(buf, arow * LPAD + q4 * 8);
        }
        f16x8 bf[4];
#pragma unroll
        for (int ni = 0; ni < 4; ++ni) {
            int brow = wn * 64 + ni * 16 + ln;
            bf[ni] = *(const f16x8*)&BSHF(buf, brow * LPAD + q4 * 8);
        }
#pragma unroll
        for (int mi = 0; mi < 2; ++mi)
#pragma unroll
            for (int ni = 0; ni < 4; ++ni)
                acc[mi][ni] = __builtin_amdgcn_mfma_f32_16x16x32_f16(af[mi], bf[ni], acc[mi][ni], 0, 0, 0);
    }

    // epilogue: C/D layout col = ln, row = q4*4 + r (m89/m91)
#pragma unroll
    for (int ni = 0; ni < 4; ++ni) {
        int col = n0 + wn * 64 + ni * 16 + ln;
#pragma unroll
        for (int mi = 0; mi < 2; ++mi) {
#pragma unroll
            for (int r = 0; r < 4; ++r) {
                int row_g = m0 + wm * 32 + mi * 16 + q4 * 4 + r;
                C[(size_t)row_g * ldc + col] = (OT)acc[mi][ni][r];
            }
        }
    }
#undef ASHF
#undef BSHF
}

// ---------------------------------------------------------------------------
// R19 super-kernel: mixed grid of knn-partial blocks (VALU-bound) and the two
// independent GEMMs (MFMA/memory-bound). blockIdx%9: 0..3 -> knn, 4..8 -> gemm.
// ---------------------------------------------------------------------------
__global__ __launch_bounds__(256, 4) void fused_knn_gemm_kernel(
    const float* __restrict__ xyz1, const float4* __restrict__ packed,
    float* __restrict__ pd0, float* __restrict__ pd1, float* __restrict__ pd2,
    int* __restrict__ pi0, int* __restrict__ pi1, int* __restrict__ pi2,
    const float* __restrict__ points2, const float* __restrict__ points1,
    const _Float16* __restrict__ W1c, _Float16* __restrict__ P2h,
    _Float16* __restrict__ temph)
{
    __shared__ _Float16 smem[SMEM_ELEMS];            // 30 KB (gemm branches)
    const int g = blockIdx.x;
    const int grp = g / 9, l9 = g % 9;
    const int tid = threadIdx.x;

    if (l9 < 4) {
        knn_partial_body(grp * 4 + l9, tid, xyz1, packed,
                         pd0, pd1, pd2, pi0, pi1, pi2);
    } else {
        int gi = grp * 5 + (l9 - 4);                 // 0..2559
        if (gi < P2_BLOCKS) {
            // P2 = points2 @ W1[:,128:]^T  [16384 x 256], K=256, f16 out
            gemm_body<256, float, _Float16>(smem, gi & 255, gi >> 8, tid,
                points2, D2, W1c + D1, D1 + D2, P2h, C1);
        } else {
            gi -= P2_BLOCKS;                          // 0..2047
            // temp = points1 @ W1[:,:128]^T  [65536 x 256], K=128, f16 out
            gemm_body<128, float, _Float16>(smem, gi & 1023, gi >> 10, tid,
                points1, D1, W1c, D1 + D2, temph, C1);
        }
    }
}

// ---------------------------------------------------------------------------
// R21: fused merge + interp + bias + BN1-stats kernel.
// Phase A (32 threads): per-row 16-chunk merge (ascending chunk order,
// ascending j within chunk, strict '<' — identical scan order to a full
// ascending pass) -> idx/w in LDS. Phase B (all 256): interp from LDS idx/w.
// ---------------------------------------------------------------------------
__global__ __launch_bounds__(256, 8) void merge_interp_kernel(
    const float* __restrict__ pd0, const float* __restrict__ pd1, const float* __restrict__ pd2,
    const int* __restrict__ pi0, const int* __restrict__ pi1, const int* __restrict__ pi2,
    const _Float16* __restrict__ temp,  // [MTOT x C1] f16 gemm result
    const _Float16* __restrict__ P2,    // [BB*SS x C1] f16
    const float* __restrict__ bias,
    _Float16* __restrict__ Y,           // [MTOT x C1] f16
    float* __restrict__ sumO, float* __restrict__ sqO)
{
#pragma clang fp contract(off)
    __shared__ float sred[2 * C1];      // 2 KB
    __shared__ int   lidx[32][3];
    __shared__ float lw[32][3];
    const int tid = threadIdx.x;
    const int m0  = blockIdx.x * 32;

    sred[tid] = 0.0f; sred[tid + 256] = 0.0f;

    if (tid < 32) {                     // Phase A: merge row m0+tid
        int m = m0 + tid;
        int b = m / NN;
        float d0 = pd0[m], d1 = pd1[m], d2 = pd2[m];
        int   i0 = pi0[m], i1 = pi1[m], i2 = pi2[m];
#pragma unroll
        for (int c = 1; c < NCH; ++c) {
            size_t oc = (size_t)c * MTOT + m;
            float da = pd0[oc], db = pd1[oc], dc = pd2[oc];
            int   sa = pi0[oc], sb = pi1[oc], scv = pi2[oc];
            {
                float d = da; int s = sa;
                bool c0 = d < d0, c1 = d < d1, c2 = d < d2;
                d2 = c1 ? d1 : (c2 ? d : d2);  i2 = c1 ? i1 : (c2 ? s : i2);
                d1 = c0 ? d0 : (c1 ? d : d1);  i1 = c0 ? i0 : (c1 ? s : i1);
                d0 = c0 ? d : d0;              i0 = c0 ? s : i0;
            }
            {
                float d = db; int s = sb;
                bool c0 = d < d0, c1 = d < d1, c2 = d < d2;
                d2 = c1 ? d1 : (c2 ? d : d2);  i2 = c1 ? i1 : (c2 ? s : i2);
                d1 = c0 ? d0 : (c1 ? d : d1);  i1 = c0 ? i0 : (c1 ? s : i1);
                d0 = c0 ? d : d0;              i0 = c0 ? s : i0;
            }
            {
                float d = dc; int s = scv;
                bool c0 = d < d0, c1 = d < d1, c2 = d < d2;
                d2 = c1 ? d1 : (c2 ? d : d2);  i2 = c1 ? i1 : (c2 ? s : i2);
                d1 = c0 ? d0 : (c1 ? d : d1);  i1 = c0 ? i0 : (c1 ? s : i1);
                d0 = c0 ? d : d0;              i0 = c0 ? s : i0;
            }
        }
        float r0 = 1.0f / (d0 + 1e-8f);
        float r1 = 1.0f / (d1 + 1e-8f);
        float r2 = 1.0f / (d2 + 1e-8f);
        float inv = 1.0f / ((r0 + r1) + r2);
        lidx[tid][0] = b * SS + i0;
        lidx[tid][1] = b * SS + i1;
        lidx[tid][2] = b * SS + i2;
        lw[tid][0] = r0 * inv;
        lw[tid][1] = r1 * inv;
        lw[tid][2] = r2 * inv;
    }
    __syncthreads();

    // Phase B: interp + bias + f16 out + BN1 stats
    const int sl = tid & 31;            // col slice (8 cols)
    const int rg = tid >> 5;            // 0..7

    float bv[8];
    *(float4*)&bv[0] = *(const float4*)(bias + sl * 8);
    *(float4*)&bv[4] = *(const float4*)(bias + sl * 8 + 4);

    float sAcc[8]  = {0.f,0.f,0.f,0.f,0.f,0.f,0.f,0.f};
    float s2Acc[8] = {0.f,0.f,0.f,0.f,0.f,0.f,0.f,0.f};

#pragma unroll
    for (int rr = 0; rr < 4; ++rr) {
        const int lr = rg * 4 + rr;     // 0..31
        const int row = m0 + lr;
        int   ia = lidx[lr][0], ib = lidx[lr][1], ic = lidx[lr][2];
        float wa = lw[lr][0],   wb = lw[lr][1],   wc = lw[lr][2];

        f16x8 av = *(const f16x8*)(temp + (size_t)row * C1 + sl * 8);
        f16x8 pa = *(const f16x8*)(P2 + (size_t)ia * C1 + sl * 8);
        f16x8 pb = *(const f16x8*)(P2 + (size_t)ib * C1 + sl * 8);
        f16x8 pc = *(const f16x8*)(P2 + (size_t)ic * C1 + sl * 8);

        f16x8 outv;
#pragma unroll
        for (int i = 0; i < 8; ++i) {
            float v = (float)av[i];
            v += wa * (float)pa[i];
            v += wb * (float)pb[i];
            v += wc * (float)pc[i];
            v += bv[i];
            outv[i] = (_Float16)v;
            sAcc[i]  += v;
            s2Acc[i] += v * v;
        }
        *(f16x8*)(Y + (size_t)row * C1 + sl * 8) = outv;
    }

#pragma unroll
    for (int i = 0; i < 8; ++i) {
        atomicAdd(&sred[sl * 8 + i],       sAcc[i]);
        atomicAdd(&sred[256 + sl * 8 + i], s2Acc[i]);
    }
    __syncthreads();
    atomicAdd(&sumO[tid], sred[tid]);
    atomicAdd(&sqO[tid],  sred[tid + 256]);
}

// ---------------------------------------------------------------------------
// Fused-stats fp16 MFMA GEMM (bn2 path): in-block finalize1, BN+ReLU on A,
// BN2 stats atomics out.
// ---------------------------------------------------------------------------
template<int K>
__global__ __launch_bounds__(256, 4) void gemm_bn2_kernel(
    const _Float16* __restrict__ A, int lda,
    const _Float16* __restrict__ W, int ldw,
    float* __restrict__ C, int ldc,
    const float* __restrict__ bias,
    const float* __restrict__ sum1, const float* __restrict__ sq1,
    const float* __restrict__ g1, const float* __restrict__ beta1,
    float* __restrict__ sumO, float* __restrict__ sqO)
{
    __shared__ _Float16 Ash[2][64 * LPAD];
    __shared__ _Float16 Bsh[2][128 * LPAD];
    __shared__ float scA[C1], shA[C1];     // 2 KB: in-block finalize1

    const int tid = threadIdx.x;
    {   // scale1/shift1 from BN1 sums (256 channels, one per thread)
        float invM = 1.0f / (float)MTOT;
        float mean = sum1[tid] * invM;
        float var = fmaxf(sq1[tid] * invM - mean * mean, 0.0f);
        float rstd = 1.0f / sqrtf(var + 1e-5f);
        float sc = g1[tid] * rstd;
        scA[tid] = sc;
        shA[tid] = beta1[tid] - mean * sc;
    }
    __syncthreads();

    const int m0 = blockIdx.x * 64;
    const int n0 = blockIdx.y * 128;
    const int wave = tid >> 6, lane = tid & 63;
    const int ln = lane & 15, q4 = lane >> 4;
    const int wm = wave & 1, wn = wave >> 1;

    const int ar = tid >> 2, ak = (tid & 3) * 8;
    const int br = tid >> 1, bk = (tid & 1) * 16;

    f32x4 acc[2][4] = {};
    f16x8  avH;
    f16x8  bvA[2];

    {
        avH = *(const f16x8*)(A + (size_t)(m0 + ar) * lda + ak);
        const _Float16* bp = W + (size_t)(n0 + br) * ldw + bk;
        bvA[0] = *(const f16x8*)bp;
        bvA[1] = *(const f16x8*)(bp + 8);
    }

    for (int k0 = 0; k0 < K; k0 += 32) {
        const int buf = (k0 >> 5) & 1;
        {
            float av[8];
#pragma unroll
            for (int i = 0; i < 8; ++i) av[i] = (float)avH[i];
#pragma unroll
            for (int i = 0; i < 8; ++i) {
                float sc = scA[k0 + ak + i];
                float sh = shA[k0 + ak + i];
                av[i] = fmaxf(av[i] * sc + sh, 0.0f);
            }
            f16x8 vh;
#pragma unroll
            for (int i = 0; i < 8; ++i) vh[i] = (_Float16)av[i];
            *(f16x8*)&Ash[buf][ar * LPAD + ak] = vh;
            *(f16x8*)&Bsh[buf][br * LPAD + bk]     = bvA[0];
            *(f16x8*)&Bsh[buf][br * LPAD + bk + 8] = bvA[1];
        }
        __syncthreads();

        if (k0 + 32 < K) {
            avH = *(const f16x8*)(A + (size_t)(m0 + ar) * lda + (k0 + 32) + ak);
            const _Float16* bp = W + (size_t)(n0 + br) * ldw + (k0 + 32) + bk;
            bvA[0] = *(const f16x8*)bp;
            bvA[1] = *(const f16x8*)(bp + 8);
        }

        f16x8 af[2];
#pragma unroll
        for (int mi = 0; mi < 2; ++mi) {
            int arow = wm * 32 + mi * 16 + ln;
            af[mi] = *(const f16x8*)&Ash[buf][arow * LPAD + q4 * 8];
        }
        f16x8 bf[4];
#pragma unroll
        for (int ni = 0; ni < 4; ++ni) {
            int brow = wn * 64 + ni * 16 + ln;
            bf[ni] = *(const f16x8*)&Bsh[buf][brow * LPAD + q4 * 8];
        }
#pragma unroll
        for (int mi = 0; mi < 2; ++mi)
#pragma unroll
            for (int ni = 0; ni < 4; ++ni)
                acc[mi][ni] = __builtin_amdgcn_mfma_f32_16x16x32_f16(af[mi], bf[ni], acc[mi][ni], 0, 0, 0);
    }

#pragma unroll
    for (int ni = 0; ni < 4; ++ni) {
        int col = n0 + wn * 64 + ni * 16 + ln;
        float vb = bias[col];
        float s = 0.0f, s2 = 0.0f;
#pragma unroll
        for (int mi = 0; mi < 2; ++mi) {
#pragma unroll
            for (int r = 0; r < 4; ++r) {
                int row_g = m0 + wm * 32 + mi * 16 + q4 * 4 + r;
                float v = acc[mi][ni][r] + vb;
                C[(size_t)row_g * ldc + col] = v;
                s += v; s2 += v * v;
            }
        }
        s  += __shfl_xor(s, 16);  s  += __shfl_xor(s, 32);
        s2 += __shfl_xor(s2, 16); s2 += __shfl_xor(s2, 32);
        if (q4 == 0) {
            atomicAdd(&sumO[col], s);
            atomicAdd(&sqO[col], s2);
        }
    }
}

// ---------------------------------------------------------------------------
// bnrelu with in-block finalize2: scale2/shift2 from BN2 sums per block.
// ---------------------------------------------------------------------------
__global__ __launch_bounds__(256) void bnrelu_kernel(
    float* __restrict__ X, int total4, int C,
    const float* __restrict__ sum2, const float* __restrict__ sq2,
    const float* __restrict__ g2, const float* __restrict__ beta2)
{
    __shared__ float sc2[C2], sh2[C2];     // 1 KB
    const int tid = threadIdx.x;
    if (tid < C2) {
        float invM = 1.0f / (float)MTOT;
        float mean = sum2[tid] * invM;
        float var = fmaxf(sq2[tid] * invM - mean * mean, 0.0f);
        float rstd = 1.0f / sqrtf(var + 1e-5f);
        float sc = g2[tid] * rstd;
        sc2[tid] = sc;
        sh2[tid] = beta2[tid] - mean * sc;
    }
    __syncthreads();

    int i = blockIdx.x * 256 + tid;
    if (i >= total4) return;
    float4 v = ((const float4*)X)[i];
    int c = (i * 4) & (C - 1);      // C pow2, 4 | C -> no wrap within the 4
    v.x = fmaxf(v.x * sc2[c+0] + sh2[c+0], 0.0f);
    v.y = fmaxf(v.y * sc2[c+1] + sh2[c+1], 0.0f);
    v.z = fmaxf(v.z * sc2[c+2] + sh2[c+2], 0.0f);
    v.w = fmaxf(v.w * sc2[c+3] + sh2[c+3], 0.0f);
    ((float4*)X)[i] = v;
}

// ---------------------------------------------------------------------------
extern "C" void kernel_launch(void* const* d_in, const int* in_sizes, int n_in,
                              void* d_out, int out_size, void* d_ws, size_t ws_size,
                              hipStream_t stream) {
    const float* xyz1    = (const float*)d_in[0];
    const float* xyz2    = (const float*)d_in[1];
    const float* points1 = (const float*)d_in[2];
    const float* points2 = (const float*)d_in[3];
    const float* W1      = (const float*)d_in[4];
    const float* b1      = (const float*)d_in[5];
    const float* g1      = (const float*)d_in[6];
    const float* beta1   = (const float*)d_in[7];
    const float* W2      = (const float*)d_in[8];
    const float* b2      = (const float*)d_in[9];
    const float* g2      = (const float*)d_in[10];
    const float* beta2   = (const float*)d_in[11];
    float* out = (float*)d_out;

    // ws layout (byte offsets, 16B-aligned)
    char* ws = (char*)d_ws;
    size_t off = 0;
    _Float16* P2h = (_Float16*)(ws + off);    off += (size_t)BB*SS*C1*2;    // 8 MB
    _Float16* y1h = (_Float16*)(ws + off);    off += (size_t)MTOT*C1*2;     // 32 MB
    _Float16* temph = (_Float16*)(ws + off);  off += (size_t)MTOT*C1*2;     // 32 MB
    float* stats = (float*)(ws + off);        off += 1024*4;
    float* sum1 = stats;            // 256
    float* sq1  = stats + 256;      // 256
    float* sum2 = stats + 512;      // 128
    float* sq2  = stats + 640;      // 128
    float4* packed = (float4*)(ws + off);     off += (size_t)BB*SS*16;      // 1 MB
    _Float16* W1c = (_Float16*)(ws + off);    off += (size_t)C1*(D1+D2)*2;
    _Float16* W2c = (_Float16*)(ws + off);    off += (size_t)C2*C1*2;
    off = (off + 255) & ~(size_t)255;
    // knn partials: dedicated (R21 — merge+interp fused kernel reads these
    // while writing y1h, so no aliasing allowed). 6 planes = 25.2 MB.
    float* pd0 = (float*)(ws + off);          off += (size_t)NCH*MTOT*4;
    float* pd1 = (float*)(ws + off);          off += (size_t)NCH*MTOT*4;
    float* pd2 = (float*)(ws + off);          off += (size_t)NCH*MTOT*4;
    int*   pi0 = (int*)(ws + off);            off += (size_t)NCH*MTOT*4;
    int*   pi1 = (int*)(ws + off);            off += (size_t)NCH*MTOT*4;
    int*   pi2 = (int*)(ws + off);            off += (size_t)NCH*MTOT*4;

    hipMemsetAsync(stats, 0, 768 * sizeof(float), stream);

    // setup: pack + wcvt in one launch (covers BB*SS + C1*(D1+D2) threads)
    setup_kernel<<<(BB*SS + C1*(D1+D2) + 255)/256, 256, 0, stream>>>(
        xyz2, packed, W1, W2, W1c, W2c);

    // super-kernel: knn partial + P2 GEMM + temp GEMM, mixed grid
    fused_knn_gemm_kernel<<<FAT_BLOCKS, 256, 0, stream>>>(
        xyz1, packed, pd0, pd1, pd2, pi0, pi1, pi2,
        points2, points1, W1c, P2h, temph);

    // merge + interp + b1 + BN1 stats, one kernel
    merge_interp_kernel<<<MTOT/32, 256, 0, stream>>>(
        pd0, pd1, pd2, pi0, pi1, pi2,
        temph, P2h, b1, y1h, sum1, sq1);

    // out = relu(bn1(y1)) @ W2^T + b2;  fp32 out; in-block finalize1 + BN2 stats
    gemm_bn2_kernel<256><<<dim3(MTOT/64, C2/128), 256, 0, stream>>>(
        y1h, C1, W2c, C1, out, C2,
        b2, sum1, sq1, g1, beta1, sum2, sq2);

    // bnrelu with in-block finalize2
    bnrelu_kernel<<<(MTOT*C2/4)/256, 256, 0, stream>>>(
        out, MTOT*C2/4, C2, sum2, sq2, g2, beta2);
}

// Round 17
// 316.838 us; speedup vs baseline: 2.2038x; 1.0010x over previous
//
#include <hip/hip_runtime.h>
#include <hip/hip_bf16.h>
#include <math.h>

// Problem constants (fixed by setup_inputs)
#define BB 4
#define NN 16384
#define SS 4096
#define D1 128
#define D2 256
#define C1 256   // mlp[0]
#define C2 128   // mlp[1]
#define MTOT (BB*NN)   // 65536

// knn decomposition (R12 scalar-load engine; R19 mixed-grid fusion; R20 f16
// temp + folded finalizes; R21 merge fused into interp; R23: f16 y2
// intermediate — R22's cooperative tail REVERTED, launch was dropped under
// graph capture -> all-zero out).
#define QPT 2              // queries per thread
#define SCH 256            // candidates per chunk
#define NCH (SS/SCH)       // 16 chunks
#define LB  4              // candidates per scalar load batch (16 dwords)

#define P2_BLOCKS   512    // (BB*SS)/64 x C1/128 = 256 x 2
#define FAT_BLOCKS  4608   // 512 groups of (4 knn + 5 gemm)

typedef _Float16 f16x8 __attribute__((ext_vector_type(8)));
typedef float f32x4  __attribute__((ext_vector_type(4)));

#define LPAD 40            // LDS row stride in fp16 elems (80B, 16B-aligned)
#define SMEM_ELEMS (2*64*LPAD + 2*128*LPAD)   // 15360 f16 = 30 KB

// ---------------------------------------------------------------------------
// setup: pack xyz2 -> {-2x,-2y,-2z,||p||^2} (bit-exact pow2 scaling) + wcvt.
// ---------------------------------------------------------------------------
__global__ __launch_bounds__(256) void setup_kernel(
    const float* __restrict__ xyz2, float4* __restrict__ packed,
    const float* __restrict__ W1, const float* __restrict__ W2,
    _Float16* __restrict__ W1c, _Float16* __restrict__ W2c)
{
#pragma clang fp contract(off)
    int i = blockIdx.x * 256 + threadIdx.x;
    if (i < BB * SS) {
        float px = xyz2[(size_t)i*3+0], py = xyz2[(size_t)i*3+1], pz = xyz2[(size_t)i*3+2];
        float pp = (px*px + py*py) + pz*pz;
        packed[i] = make_float4(-2.0f*px, -2.0f*py, -2.0f*pz, pp);
    }
    int j = i - BB * SS;
    if (j >= 0 && j < C1 * (D1 + D2)) W1c[j] = (_Float16)W1[j];
    if (j >= 0 && j < C2 * C1)        W2c[j] = (_Float16)W2[j];
}

// ---------------------------------------------------------------------------
// knn pass-1 body (R12 engine): exact fp32 distances (contract off),
// min/med3 + cndmask chains, strict '<' ascending order (== lax.top_k).
// HARD CONSTRAINT (R7): never approximate the distance or the comparison.
// ---------------------------------------------------------------------------
__device__ __forceinline__ void knn_partial_body(
    int kb, int tid,
    const float* __restrict__ xyz1, const float4* __restrict__ packed,
    float* __restrict__ pd0, float* __restrict__ pd1, float* __restrict__ pd2,
    int* __restrict__ pi0, int* __restrict__ pi1, int* __restrict__ pi2)
{
#pragma clang fp contract(off)
    const int qblocks = NN / (256 * QPT);            // 32
    const int b  = kb / (qblocks * NCH);
    const int r  = kb % (qblocks * NCH);
    const int qc = r / NCH;
    const int sc = r % NCH;

    const float4* __restrict__ src = packed + (size_t)b * SS + sc * SCH;

    float qx[QPT], qy[QPT], qz[QPT], qq[QPT];
    float e0[QPT], e1[QPT], e2[QPT];
    int   j0[QPT], j1[QPT], j2[QPT];
#pragma unroll
    for (int q = 0; q < QPT; ++q) {
        int n = qc * (256 * QPT) + q * 256 + tid;
        size_t m = (size_t)b * NN + n;
        qx[q] = xyz1[m*3+0]; qy[q] = xyz1[m*3+1]; qz[q] = xyz1[m*3+2];
        qq[q] = (qx[q]*qx[q] + qy[q]*qy[q]) + qz[q]*qz[q];
        e0[q] = 3.4e38f; e1[q] = 3.4e38f; e2[q] = 3.4e38f;
        j0[q] = 0; j1[q] = 0; j2[q] = 0;
    }

    auto proc = [&](float4 p, int s) {
#pragma clang fp contract(off)
#pragma unroll
        for (int q = 0; q < QPT; ++q) {
            float cr2 = (qx[q]*p.x + qy[q]*p.y) + qz[q]*p.z;   // == -2*cr exactly
            float d = (qq[q] + cr2) + p.w;
            d = fmaxf(d, 0.0f);
            bool c0 = d < e0[q], c1 = d < e1[q], c2 = d < e2[q];
            j2[q] = c1 ? j1[q] : (c2 ? s : j2[q]);
            j1[q] = c0 ? j0[q] : (c1 ? s : j1[q]);
            j0[q] = c0 ? s : j0[q];
            e2[q] = __builtin_amdgcn_fmed3f(e1[q], d, e2[q]);
            e1[q] = __builtin_amdgcn_fmed3f(e0[q], d, e1[q]);
            e0[q] = fminf(e0[q], d);
        }
    };

    for (int s = 0; s < SCH; s += LB) {
        float4 P0 = src[s+0];                        // uniform -> s_load
        float4 P1 = src[s+1];
        float4 P2v = src[s+2];
        float4 P3 = src[s+3];
        __builtin_amdgcn_sched_barrier(0);           // pin loads before bodies
        proc(P0, s+0);
        proc(P1, s+1);
        proc(P2v, s+2);
        proc(P3, s+3);
    }

#pragma unroll
    for (int q = 0; q < QPT; ++q) {
        int n = qc * (256 * QPT) + q * 256 + tid;
        size_t m = (size_t)b * NN + n;
        size_t o = (size_t)sc * MTOT + m;
        pd0[o] = e0[q]; pd1[o] = e1[q]; pd2[o] = e2[q];
        pi0[o] = sc*SCH + j0[q];
        pi1[o] = sc*SCH + j1[q];
        pi2[o] = sc*SCH + j2[q];
    }
}

// ---------------------------------------------------------------------------
// Plain fp16 MFMA GEMM body (no fusion), LDS pool passed in (30 KB).
// C[M x N] = A[M x K] @ W[N x K]^T. Tile 64x128, 4 waves, k-chunk 32.
// ---------------------------------------------------------------------------
template<int K, typename AT, typename OT>
__device__ __forceinline__ void gemm_body(
    _Float16* __restrict__ smem, int bx, int by, int tid,
    const AT* __restrict__ A, int lda,
    const _Float16* __restrict__ W, int ldw,
    OT* __restrict__ C, int ldc)
{
#define ASHF(b_, i_) smem[(b_)*(64*LPAD) + (i_)]
#define BSHF(b_, i_) smem[2*64*LPAD + (b_)*(128*LPAD) + (i_)]
    const int m0 = bx * 64;
    const int n0 = by * 128;
    const int wave = tid >> 6, lane = tid & 63;
    const int ln = lane & 15, q4 = lane >> 4;
    const int wm = wave & 1, wn = wave >> 1;

    const int ar = tid >> 2, ak = (tid & 3) * 8;   // A staging: 64 rows x 32k
    const int br = tid >> 1, bk = (tid & 1) * 16;  // B staging: 128 rows x 32k

    f32x4 acc[2][4] = {};

    float  avF[8];
    f16x8  avH;
    f16x8  bvA[2];

    {   // prologue prefetch k0 = 0
        if constexpr (__is_same(AT, float)) {
            const float* ap = A + (size_t)(m0 + ar) * lda + ak;
            *(float4*)&avF[0] = *(const float4*)ap;
            *(float4*)&avF[4] = *(const float4*)(ap + 4);
        } else {
            avH = *(const f16x8*)(A + (size_t)(m0 + ar) * lda + ak);
        }
        const _Float16* bp = W + (size_t)(n0 + br) * ldw + bk;
        bvA[0] = *(const f16x8*)bp;
        bvA[1] = *(const f16x8*)(bp + 8);
    }

    for (int k0 = 0; k0 < K; k0 += 32) {
        const int buf = (k0 >> 5) & 1;
        {
            float av[8];
            if constexpr (__is_same(AT, float)) {
#pragma unroll
                for (int i = 0; i < 8; ++i) av[i] = avF[i];
            } else {
#pragma unroll
                for (int i = 0; i < 8; ++i) av[i] = (float)avH[i];
            }
            f16x8 vh;
#pragma unroll
            for (int i = 0; i < 8; ++i) vh[i] = (_Float16)av[i];
            *(f16x8*)&ASHF(buf, ar * LPAD + ak) = vh;
            *(f16x8*)&BSHF(buf, br * LPAD + bk)     = bvA[0];
            *(f16x8*)&BSHF(buf, br * LPAD + bk + 8) = bvA[1];
        }
        __syncthreads();

        if (k0 + 32 < K) {
            if constexpr (__is_same(AT, float)) {
                const float* ap = A + (size_t)(m0 + ar) * lda + (k0 + 32) + ak;
                *(float4*)&avF[0] = *(const float4*)ap;
                *(float4*)&avF[4] = *(const float4*)(ap + 4);
            } else {
                avH = *(const f16x8*)(A + (size_t)(m0 + ar) * lda + (k0 + 32) + ak);
            }
            const _Float16* bp = W + (size_t)(n0 + br) * ldw + (k0 + 32) + bk;
            bvA[0] = *(const f16x8*)bp;
            bvA[1] = *(const f16x8*)(bp + 8);
        }

        f16x8 af[2];
#pragma unroll
        for (int mi = 0; mi < 2; ++mi) {
            int arow = wm * 32 + mi * 16 + ln;
            af[mi] = *(const f16x8*)&ASHF(buf, arow * LPAD + q4 * 8);
        }
        f16x8 bf[4];
#pragma unroll
        for (int ni = 0; ni < 4; ++ni) {
            int brow = wn * 64 + ni * 16 + ln;
            bf[ni] = *(const f16x8*)&BSHF(buf, brow * LPAD + q4 * 8);
        }
#pragma unroll
        for (int mi = 0; mi < 2; ++mi)
#pragma unroll
            for (int ni = 0; ni < 4; ++ni)
                acc[mi][ni] = __builtin_amdgcn_mfma_f32_16x16x32_f16(af[mi], bf[ni], acc[mi][ni], 0, 0, 0);
    }

    // epilogue: C/D layout col = ln, row = q4*4 + r (m89/m91)
#pragma unroll
    for (int ni = 0; ni < 4; ++ni) {
        int col = n0 + wn * 64 + ni * 16 + ln;
#pragma unroll
        for (int mi = 0; mi < 2; ++mi) {
#pragma unroll
            for (int r = 0; r < 4; ++r) {
                int row_g = m0 + wm * 32 + mi * 16 + q4 * 4 + r;
                C[(size_t)row_g * ldc + col] = (OT)acc[mi][ni][r];
            }
        }
    }
#undef ASHF
#undef BSHF
}

// ---------------------------------------------------------------------------
// R19 super-kernel: mixed grid of knn-partial blocks and the two independent
// GEMMs. blockIdx%9: 0..3 -> knn, 4..8 -> gemm.
// ---------------------------------------------------------------------------
__global__ __launch_bounds__(256, 4) void fused_knn_gemm_kernel(
    const float* __restrict__ xyz1, const float4* __restrict__ packed,
    float* __restrict__ pd0, float* __restrict__ pd1, float* __restrict__ pd2,
    int* __restrict__ pi0, int* __restrict__ pi1, int* __restrict__ pi2,
    const float* __restrict__ points2, const float* __restrict__ points1,
    const _Float16* __restrict__ W1c, _Float16* __restrict__ P2h,
    _Float16* __restrict__ temph)
{
    __shared__ _Float16 smem[SMEM_ELEMS];            // 30 KB (gemm branches)
    const int g = blockIdx.x;
    const int grp = g / 9, l9 = g % 9;
    const int tid = threadIdx.x;

    if (l9 < 4) {
        knn_partial_body(grp * 4 + l9, tid, xyz1, packed,
                         pd0, pd1, pd2, pi0, pi1, pi2);
    } else {
        int gi = grp * 5 + (l9 - 4);                 // 0..2559
        if (gi < P2_BLOCKS) {
            // P2 = points2 @ W1[:,128:]^T  [16384 x 256], K=256, f16 out
            gemm_body<256, float, _Float16>(smem, gi & 255, gi >> 8, tid,
                points2, D2, W1c + D1, D1 + D2, P2h, C1);
        } else {
            gi -= P2_BLOCKS;                          // 0..2047
            // temp = points1 @ W1[:,:128]^T  [65536 x 256], K=128, f16 out
            gemm_body<128, float, _Float16>(smem, gi & 1023, gi >> 10, tid,
                points1, D1, W1c, D1 + D2, temph, C1);
        }
    }
}

// ---------------------------------------------------------------------------
// R21: fused merge + interp + bias + BN1-stats kernel.
// Phase A (32 threads): per-row 16-chunk merge (ascending chunk order,
// ascending j within chunk, strict '<'). Phase B (all 256): interp.
// ---------------------------------------------------------------------------
__global__ __launch_bounds__(256, 8) void merge_interp_kernel(
    const float* __restrict__ pd0, const float* __restrict__ pd1, const float* __restrict__ pd2,
    const int* __restrict__ pi0, const int* __restrict__ pi1, const int* __restrict__ pi2,
    const _Float16* __restrict__ temp,  // [MTOT x C1] f16 gemm result
    const _Float16* __restrict__ P2,    // [BB*SS x C1] f16
    const float* __restrict__ bias,
    _Float16* __restrict__ Y,           // [MTOT x C1] f16
    float* __restrict__ sumO, float* __restrict__ sqO)
{
#pragma clang fp contract(off)
    __shared__ float sred[2 * C1];      // 2 KB
    __shared__ int   lidx[32][3];
    __shared__ float lw[32][3];
    const int tid = threadIdx.x;
    const int m0  = blockIdx.x * 32;

    sred[tid] = 0.0f; sred[tid + 256] = 0.0f;

    if (tid < 32) {                     // Phase A: merge row m0+tid
        int m = m0 + tid;
        int b = m / NN;
        float d0 = pd0[m], d1 = pd1[m], d2 = pd2[m];
        int   i0 = pi0[m], i1 = pi1[m], i2 = pi2[m];
#pragma unroll
        for (int c = 1; c < NCH; ++c) {
            size_t oc = (size_t)c * MTOT + m;
            float da = pd0[oc], db = pd1[oc], dc = pd2[oc];
            int   sa = pi0[oc], sb = pi1[oc], scv = pi2[oc];
            {
                float d = da; int s = sa;
                bool c0 = d < d0, c1 = d < d1, c2 = d < d2;
                d2 = c1 ? d1 : (c2 ? d : d2);  i2 = c1 ? i1 : (c2 ? s : i2);
                d1 = c0 ? d0 : (c1 ? d : d1);  i1 = c0 ? i0 : (c1 ? s : i1);
                d0 = c0 ? d : d0;              i0 = c0 ? s : i0;
            }
            {
                float d = db; int s = sb;
                bool c0 = d < d0, c1 = d < d1, c2 = d < d2;
                d2 = c1 ? d1 : (c2 ? d : d2);  i2 = c1 ? i1 : (c2 ? s : i2);
                d1 = c0 ? d0 : (c1 ? d : d1);  i1 = c0 ? i0 : (c1 ? s : i1);
                d0 = c0 ? d : d0;              i0 = c0 ? s : i0;
            }
            {
                float d = dc; int s = scv;
                bool c0 = d < d0, c1 = d < d1, c2 = d < d2;
                d2 = c1 ? d1 : (c2 ? d : d2);  i2 = c1 ? i1 : (c2 ? s : i2);
                d1 = c0 ? d0 : (c1 ? d : d1);  i1 = c0 ? i0 : (c1 ? s : i1);
                d0 = c0 ? d : d0;              i0 = c0 ? s : i0;
            }
        }
        float r0 = 1.0f / (d0 + 1e-8f);
        float r1 = 1.0f / (d1 + 1e-8f);
        float r2 = 1.0f / (d2 + 1e-8f);
        float inv = 1.0f / ((r0 + r1) + r2);
        lidx[tid][0] = b * SS + i0;
        lidx[tid][1] = b * SS + i1;
        lidx[tid][2] = b * SS + i2;
        lw[tid][0] = r0 * inv;
        lw[tid][1] = r1 * inv;
        lw[tid][2] = r2 * inv;
    }
    __syncthreads();

    // Phase B: interp + bias + f16 out + BN1 stats
    const int sl = tid & 31;            // col slice (8 cols)
    const int rg = tid >> 5;            // 0..7

    float bv[8];
    *(float4*)&bv[0] = *(const float4*)(bias + sl * 8);
    *(float4*)&bv[4] = *(const float4*)(bias + sl * 8 + 4);

    float sAcc[8]  = {0.f,0.f,0.f,0.f,0.f,0.f,0.f,0.f};
    float s2Acc[8] = {0.f,0.f,0.f,0.f,0.f,0.f,0.f,0.f};

#pragma unroll
    for (int rr = 0; rr < 4; ++rr) {
        const int lr = rg * 4 + rr;     // 0..31
        const int row = m0 + lr;
        int   ia = lidx[lr][0], ib = lidx[lr][1], ic = lidx[lr][2];
        float wa = lw[lr][0],   wb = lw[lr][1],   wc = lw[lr][2];

        f16x8 av = *(const f16x8*)(temp + (size_t)row * C1 + sl * 8);
        f16x8 pa = *(const f16x8*)(P2 + (size_t)ia * C1 + sl * 8);
        f16x8 pb = *(const f16x8*)(P2 + (size_t)ib * C1 + sl * 8);
        f16x8 pc = *(const f16x8*)(P2 + (size_t)ic * C1 + sl * 8);

        f16x8 outv;
#pragma unroll
        for (int i = 0; i < 8; ++i) {
            float v = (float)av[i];
            v += wa * (float)pa[i];
            v += wb * (float)pb[i];
            v += wc * (float)pc[i];
            v += bv[i];
            outv[i] = (_Float16)v;
            sAcc[i]  += v;
            s2Acc[i] += v * v;
        }
        *(f16x8*)(Y + (size_t)row * C1 + sl * 8) = outv;
    }

#pragma unroll
    for (int i = 0; i < 8; ++i) {
        atomicAdd(&sred[sl * 8 + i],       sAcc[i]);
        atomicAdd(&sred[256 + sl * 8 + i], s2Acc[i]);
    }
    __syncthreads();
    atomicAdd(&sumO[tid], sred[tid]);
    atomicAdd(&sqO[tid],  sred[tid + 256]);
}

// ---------------------------------------------------------------------------
// Fused-stats fp16 MFMA GEMM (bn2 path): in-block finalize1, BN+ReLU on A,
// BN2 stats atomics; R23: y2 stored f16 (stats from pre-rounding fp32).
// ---------------------------------------------------------------------------
template<int K>
__global__ __launch_bounds__(256, 4) void gemm_bn2_kernel(
    const _Float16* __restrict__ A, int lda,
    const _Float16* __restrict__ W, int ldw,
    _Float16* __restrict__ C, int ldc,
    const float* __restrict__ bias,
    const float* __restrict__ sum1, const float* __restrict__ sq1,
    const float* __restrict__ g1, const float* __restrict__ beta1,
    float* __restrict__ sumO, float* __restrict__ sqO)
{
    __shared__ _Float16 Ash[2][64 * LPAD];
    __shared__ _Float16 Bsh[2][128 * LPAD];
    __shared__ float scA[C1], shA[C1];     // 2 KB: in-block finalize1

    const int tid = threadIdx.x;
    {   // scale1/shift1 from BN1 sums (256 channels, one per thread)
        float invM = 1.0f / (float)MTOT;
        float mean = sum1[tid] * invM;
        float var = fmaxf(sq1[tid] * invM - mean * mean, 0.0f);
        float rstd = 1.0f / sqrtf(var + 1e-5f);
        float sc = g1[tid] * rstd;
        scA[tid] = sc;
        shA[tid] = beta1[tid] - mean * sc;
    }
    __syncthreads();

    const int m0 = blockIdx.x * 64;
    const int n0 = blockIdx.y * 128;
    const int wave = tid >> 6, lane = tid & 63;
    const int ln = lane & 15, q4 = lane >> 4;
    const int wm = wave & 1, wn = wave >> 1;

    const int ar = tid >> 2, ak = (tid & 3) * 8;
    const int br = tid >> 1, bk = (tid & 1) * 16;

    f32x4 acc[2][4] = {};
    f16x8  avH;
    f16x8  bvA[2];

    {
        avH = *(const f16x8*)(A + (size_t)(m0 + ar) * lda + ak);
        const _Float16* bp = W + (size_t)(n0 + br) * ldw + bk;
        bvA[0] = *(const f16x8*)bp;
        bvA[1] = *(const f16x8*)(bp + 8);
    }

    for (int k0 = 0; k0 < K; k0 += 32) {
        const int buf = (k0 >> 5) & 1;
        {
            float av[8];
#pragma unroll
            for (int i = 0; i < 8; ++i) av[i] = (float)avH[i];
#pragma unroll
            for (int i = 0; i < 8; ++i) {
                float sc = scA[k0 + ak + i];
                float sh = shA[k0 + ak + i];
                av[i] = fmaxf(av[i] * sc + sh, 0.0f);
            }
            f16x8 vh;
#pragma unroll
            for (int i = 0; i < 8; ++i) vh[i] = (_Float16)av[i];
            *(f16x8*)&Ash[buf][ar * LPAD + ak] = vh;
            *(f16x8*)&Bsh[buf][br * LPAD + bk]     = bvA[0];
            *(f16x8*)&Bsh[buf][br * LPAD + bk + 8] = bvA[1];
        }
        __syncthreads();

        if (k0 + 32 < K) {
            avH = *(const f16x8*)(A + (size_t)(m0 + ar) * lda + (k0 + 32) + ak);
            const _Float16* bp = W + (size_t)(n0 + br) * ldw + (k0 + 32) + bk;
            bvA[0] = *(const f16x8*)bp;
            bvA[1] = *(const f16x8*)(bp + 8);
        }

        f16x8 af[2];
#pragma unroll
        for (int mi = 0; mi < 2; ++mi) {
            int arow = wm * 32 + mi * 16 + ln;
            af[mi] = *(const f16x8*)&Ash[buf][arow * LPAD + q4 * 8];
        }
        f16x8 bf[4];
#pragma unroll
        for (int ni = 0; ni < 4; ++ni) {
            int brow = wn * 64 + ni * 16 + ln;
            bf[ni] = *(const f16x8*)&Bsh[buf][brow * LPAD + q4 * 8];
        }
#pragma unroll
        for (int mi = 0; mi < 2; ++mi)
#pragma unroll
            for (int ni = 0; ni < 4; ++ni)
                acc[mi][ni] = __builtin_amdgcn_mfma_f32_16x16x32_f16(af[mi], bf[ni], acc[mi][ni], 0, 0, 0);
    }

#pragma unroll
    for (int ni = 0; ni < 4; ++ni) {
        int col = n0 + wn * 64 + ni * 16 + ln;
        float vb = bias[col];
        float s = 0.0f, s2 = 0.0f;
#pragma unroll
        for (int mi = 0; mi < 2; ++mi) {
#pragma unroll
            for (int r = 0; r < 4; ++r) {
                int row_g = m0 + wm * 32 + mi * 16 + q4 * 4 + r;
                float v = acc[mi][ni][r] + vb;
                C[(size_t)row_g * ldc + col] = (_Float16)v;
                s += v; s2 += v * v;
            }
        }
        s  += __shfl_xor(s, 16);  s  += __shfl_xor(s, 32);
        s2 += __shfl_xor(s2, 16); s2 += __shfl_xor(s2, 32);
        if (q4 == 0) {
            atomicAdd(&sumO[col], s);
            atomicAdd(&sqO[col], s2);
        }
    }
}

// ---------------------------------------------------------------------------
// bnrelu with in-block finalize2: reads f16 y2 (R23), writes fp32 out.
// ---------------------------------------------------------------------------
__global__ __launch_bounds__(256) void bnrelu_kernel(
    const _Float16* __restrict__ Y2, float* __restrict__ out, int total8,
    const float* __restrict__ sum2, const float* __restrict__ sq2,
    const float* __restrict__ g2, const float* __restrict__ beta2)
{
    __shared__ float sc2[C2], sh2[C2];     // 1 KB
    const int tid = threadIdx.x;
    if (tid < C2) {
        float invM = 1.0f / (float)MTOT;
        float mean = sum2[tid] * invM;
        float var = fmaxf(sq2[tid] * invM - mean * mean, 0.0f);
        float rstd = 1.0f / sqrtf(var + 1e-5f);
        float sc = g2[tid] * rstd;
        sc2[tid] = sc;
        sh2[tid] = beta2[tid] - mean * sc;
    }
    __syncthreads();

    int i = blockIdx.x * 256 + tid;
    if (i >= total8) return;
    f16x8 v8 = ((const f16x8*)Y2)[i];
    int c = (i * 8) & (C2 - 1);     // C2 pow2, 8 | C2 -> no wrap within the 8
    float o[8];
#pragma unroll
    for (int j = 0; j < 8; ++j)
        o[j] = fmaxf((float)v8[j] * sc2[c + j] + sh2[c + j], 0.0f);
    float* op = out + (size_t)i * 8;
    *(float4*)op       = *(float4*)&o[0];
    *(float4*)(op + 4) = *(float4*)&o[4];
}

// ---------------------------------------------------------------------------
extern "C" void kernel_launch(void* const* d_in, const int* in_sizes, int n_in,
                              void* d_out, int out_size, void* d_ws, size_t ws_size,
                              hipStream_t stream) {
    const float* xyz1    = (const float*)d_in[0];
    const float* xyz2    = (const float*)d_in[1];
    const float* points1 = (const float*)d_in[2];
    const float* points2 = (const float*)d_in[3];
    const float* W1      = (const float*)d_in[4];
    const float* b1      = (const float*)d_in[5];
    const float* g1      = (const float*)d_in[6];
    const float* beta1   = (const float*)d_in[7];
    const float* W2      = (const float*)d_in[8];
    const float* b2      = (const float*)d_in[9];
    const float* g2      = (const float*)d_in[10];
    const float* beta2   = (const float*)d_in[11];
    float* out = (float*)d_out;

    // ws layout (byte offsets, 16B-aligned)
    char* ws = (char*)d_ws;
    size_t off = 0;
    _Float16* P2h = (_Float16*)(ws + off);    off += (size_t)BB*SS*C1*2;    // 8 MB
    _Float16* y1h = (_Float16*)(ws + off);    off += (size_t)MTOT*C1*2;     // 32 MB
    _Float16* temph = (_Float16*)(ws + off);  off += (size_t)MTOT*C1*2;     // 32 MB
    _Float16* y2h = (_Float16*)(ws + off);    off += (size_t)MTOT*C2*2;     // 16 MB
    float* stats = (float*)(ws + off);        off += 1024*4;
    float* sum1 = stats;            // 256
    float* sq1  = stats + 256;      // 256
    float* sum2 = stats + 512;      // 128
    float* sq2  = stats + 640;      // 128
    float4* packed = (float4*)(ws + off);     off += (size_t)BB*SS*16;      // 1 MB
    _Float16* W1c = (_Float16*)(ws + off);    off += (size_t)C1*(D1+D2)*2;
    _Float16* W2c = (_Float16*)(ws + off);    off += (size_t)C2*C1*2;
    off = (off + 255) & ~(size_t)255;
    // knn partials: dedicated region (merge+interp reads while writing y1h)
    float* pd0 = (float*)(ws + off);          off += (size_t)NCH*MTOT*4;
    float* pd1 = (float*)(ws + off);          off += (size_t)NCH*MTOT*4;
    float* pd2 = (float*)(ws + off);          off += (size_t)NCH*MTOT*4;
    int*   pi0 = (int*)(ws + off);            off += (size_t)NCH*MTOT*4;
    int*   pi1 = (int*)(ws + off);            off += (size_t)NCH*MTOT*4;
    int*   pi2 = (int*)(ws + off);            off += (size_t)NCH*MTOT*4;

    hipMemsetAsync(stats, 0, 1024 * sizeof(float), stream);

    // setup: pack + wcvt in one launch
    setup_kernel<<<(BB*SS + C1*(D1+D2) + 255)/256, 256, 0, stream>>>(
        xyz2, packed, W1, W2, W1c, W2c);

    // super-kernel: knn partial + P2 GEMM + temp GEMM, mixed grid
    fused_knn_gemm_kernel<<<FAT_BLOCKS, 256, 0, stream>>>(
        xyz1, packed, pd0, pd1, pd2, pi0, pi1, pi2,
        points2, points1, W1c, P2h, temph);

    // merge + interp + b1 + BN1 stats, one kernel
    merge_interp_kernel<<<MTOT/32, 256, 0, stream>>>(
        pd0, pd1, pd2, pi0, pi1, pi2,
        temph, P2h, b1, y1h, sum1, sq1);

    // y2 = relu(bn1(y1)) @ W2^T + b2;  f16 out; in-block finalize1 + BN2 stats
    gemm_bn2_kernel<256><<<dim3(MTOT/64, C2/128), 256, 0, stream>>>(
        y1h, C1, W2c, C1, y2h, C2,
        b2, sum1, sq1, g1, beta1, sum2, sq2);

    // out = relu(bn2(y2))  (f16 in, fp32 out; in-block finalize2)
    bnrelu_kernel<<<(MTOT*C2/8)/256, 256, 0, stream>>>(
        y2h, out, MTOT*C2/8, sum2, sq2, g2, beta2);
}